// Round 1
// baseline (829.548 us; speedup 1.0000x reference)
//
#include <hip/hip_runtime.h>
#include <hip/hip_bf16.h>

#define NNODE 80000
#define NEDGE 1280000
#define D 64
#define EPS 1e-8f

__device__ __forceinline__ float wave_sum64(float v) {
    #pragma unroll
    for (int d = 1; d < 64; d <<= 1) v += __shfl_xor(v, d);
    return v;
}

// ---------------- CSR build ----------------
__global__ __launch_bounds__(256) void k_hist(const int* __restrict__ dst,
                                              int* __restrict__ deg, int e) {
    int i = blockIdx.x * blockDim.x + threadIdx.x;
    if (i < e) atomicAdd(&deg[dst[i]], 1);
}

// single-block exclusive scan: deg[0..n-1] -> off[0..n], cursor = off copy
__global__ __launch_bounds__(1024) void k_scan(const int* __restrict__ deg,
                                               int* __restrict__ off,
                                               int* __restrict__ cursor, int n) {
    __shared__ int sm[1024];
    __shared__ int s_carry;
    int tid = threadIdx.x;
    if (tid == 0) s_carry = 0;
    __syncthreads();
    for (int base = 0; base < n; base += 1024) {
        int c = s_carry;
        int i = base + tid;
        int v = (i < n) ? deg[i] : 0;
        sm[tid] = v;
        __syncthreads();
        #pragma unroll
        for (int d = 1; d < 1024; d <<= 1) {
            int t = (tid >= d) ? sm[tid - d] : 0;
            __syncthreads();
            sm[tid] += t;
            __syncthreads();
        }
        int incl = sm[tid];
        if (i < n) { int e = c + incl - v; off[i] = e; cursor[i] = e; }
        int total = sm[1023];
        __syncthreads();
        if (tid == 0) s_carry = c + total;
        __syncthreads();
    }
    if (tid == 0) off[n] = s_carry;
}

__global__ __launch_bounds__(256) void k_fill(const int* __restrict__ src,
                                              const int* __restrict__ dst,
                                              const float* __restrict__ w,
                                              int* __restrict__ cursor,
                                              int* __restrict__ esrc,
                                              float* __restrict__ ew, int e) {
    int i = blockIdx.x * blockDim.x + threadIdx.x;
    if (i < e) {
        int d = dst[i];
        int pos = atomicAdd(&cursor[d], 1);
        esrc[pos] = src[i];
        ew[pos] = w[i];
    }
}

// ---------------- Lorentz linear (one wave per node, lane = out dim) -------
// MODE 0: input = x (N x 63), compute hyperboloid embed p first.
// MODE 1: input = relu(in) (N x 64).
template <int MODE>
__global__ __launch_bounds__(256) void k_linear(const float* __restrict__ in,
                                                const float* __restrict__ W,
                                                const float* __restrict__ b,
                                                const float* __restrict__ sc,
                                                float* __restrict__ out, int n) {
    __shared__ float Wt[64 * 64];     // Wt[k*64+j] = W[j*64+k]
    __shared__ float pbuf[4][64];
    int tid = threadIdx.x;
    for (int t = tid; t < 64 * 64; t += 256) {
        int j = t >> 6, k = t & 63;
        Wt[k * 64 + j] = W[t];
    }
    __syncthreads();

    int lane = tid & 63, wv = tid >> 6;
    int node = blockIdx.x * 4 + wv;
    if (node < n) {
        float p;
        if (MODE == 0) {
            float xv = (lane >= 1) ? in[node * 63 + (lane - 1)] : 0.f;
            float nrm2 = wave_sum64(xv * xv);
            float nrm = fmaxf(sqrtf(nrm2), EPS);
            float sh = sinhf(nrm);
            float ps = (lane == 0) ? 0.f : sh * xv / nrm;
            float sp2 = wave_sum64(ps * ps);
            p = (lane == 0) ? sqrtf(1.f + sp2) : ps;
        } else {
            p = fmaxf(in[node * 64 + lane], 0.f);
        }
        pbuf[wv][lane] = p;
    }
    __syncthreads();
    if (node >= n) return;

    float acc = b[lane];
    #pragma unroll 8
    for (int k = 0; k < 64; ++k)
        acc += pbuf[wv][k] * Wt[k * 64 + lane];

    float h0 = __shfl(acc, 0);
    float ls = sc[0];
    float time = 1.f / (1.f + expf(-h0)) * expf(ls) + 1.1f;
    float sp = (lane == 0) ? 0.f : acc;
    float sq = fmaxf(wave_sum64(sp * sp), EPS);
    float scale = (time * time - 1.f) / sq;
    float r = sqrtf(scale);
    out[node * 64 + lane] = (lane == 0) ? time : acc * r;
}

// ---------------- Aggregation: one wave per node, lane = dim ----------------
// FINAL 0: out = to_manifold(segsum)
// FINAL 1: h2 = to_manifold(segsum); out = to_manifold(h1 + h2)
template <int FINAL>
__global__ __launch_bounds__(256) void k_agg(const float* __restrict__ t,
                                             const int* __restrict__ off,
                                             const int* __restrict__ esrc,
                                             const float* __restrict__ ew,
                                             const float* __restrict__ h1,
                                             float* __restrict__ out, int n) {
    int lane = threadIdx.x & 63, wv = threadIdx.x >> 6;
    int node = blockIdx.x * 4 + wv;
    if (node >= n) return;
    int s0 = off[node], s1 = off[node + 1];
    float acc = 0.f;
    for (int base = s0; base < s1; base += 64) {
        int m = s1 - base;
        int cnt = (m < 64) ? m : 64;
        int src = 0; float w = 0.f;
        if (lane < cnt) { src = esrc[base + lane]; w = ew[base + lane]; }
        for (int j = 0; j < cnt; ++j) {
            int sj = __shfl(src, j);
            float wj = __shfl(w, j);
            acc += wj * t[sj * 64 + lane];
        }
    }
    float q = (lane == 0) ? -acc * acc : acc * acc;
    float inner = wave_sum64(q);
    float denom = sqrtf(fmaxf(fabsf(inner), EPS));
    float h = acc / denom;
    if (FINAL) {
        float v = h1[node * 64 + lane] + h;
        float q2 = (lane == 0) ? -v * v : v * v;
        float inner2 = wave_sum64(q2);
        float denom2 = sqrtf(fmaxf(fabsf(inner2), EPS));
        out[node * 64 + lane] = v / denom2;
    } else {
        out[node * 64 + lane] = h;
    }
}

extern "C" void kernel_launch(void* const* d_in, const int* in_sizes, int n_in,
                              void* d_out, int out_size, void* d_ws, size_t ws_size,
                              hipStream_t stream) {
    const float* x  = (const float*)d_in[0];
    const int*   ei = (const int*)d_in[1];
    const float* wE = (const float*)d_in[2];
    const float* W1 = (const float*)d_in[3];
    const float* b1 = (const float*)d_in[4];
    const float* s1 = (const float*)d_in[5];
    const float* W2 = (const float*)d_in[6];
    const float* b2 = (const float*)d_in[7];
    const float* s2 = (const float*)d_in[8];
    float* out = (float*)d_out;

    const int N = in_sizes[0] / (D - 1);
    const int E = in_sizes[2];
    const int* src = ei;
    const int* dst = ei + E;

    char* ws = (char*)d_ws;
    float* B1 = (float*)ws;                       // N*64 f32  (t1, then t2)
    float* B2 = B1 + (size_t)N * D;               // N*64 f32  (agg1 -> h1)
    int* off    = (int*)(B2 + (size_t)N * D);     // N+1
    int* cursor = off + (N + 1);                  // N
    int* deg    = cursor + N;                     // N
    int* esrc   = deg + N;                        // E
    float* ew   = (float*)(esrc + E);             // E

    hipMemsetAsync(deg, 0, (size_t)N * sizeof(int), stream);

    int gE = (E + 255) / 256;
    int gN = (N + 3) / 4;

    k_hist<<<gE, 256, 0, stream>>>(dst, deg, E);
    k_scan<<<1, 1024, 0, stream>>>(deg, off, cursor, N);
    k_fill<<<gE, 256, 0, stream>>>(src, dst, wE, cursor, esrc, ew, E);

    k_linear<0><<<gN, 256, 0, stream>>>(x, W1, b1, s1, B1, N);
    k_agg<0><<<gN, 256, 0, stream>>>(B1, off, esrc, ew, nullptr, B2, N);
    k_linear<1><<<gN, 256, 0, stream>>>(B2, W2, b2, s2, B1, N);
    k_agg<1><<<gN, 256, 0, stream>>>(B1, off, esrc, ew, B2, out, N);
}

// Round 2
// 379.634 us; speedup vs baseline: 2.1851x; 2.1851x over previous
//
#include <hip/hip_runtime.h>
#include <hip/hip_bf16.h>

#define D 64
#define EPS 1e-8f

__device__ __forceinline__ float wave_sum64(float v) {
    #pragma unroll
    for (int d = 1; d < 64; d <<= 1) v += __shfl_xor(v, d);
    return v;
}

// ---------------- CSR build ----------------
__global__ __launch_bounds__(256) void k_hist(const int* __restrict__ dst,
                                              int* __restrict__ deg, int e) {
    int i = blockIdx.x * blockDim.x + threadIdx.x;
    if (i < e) atomicAdd(&deg[dst[i]], 1);
}

// level 1: per-block exclusive scan (block-local) + block total
__global__ __launch_bounds__(1024) void k_scan1(const int* __restrict__ deg,
                                                int* __restrict__ off,
                                                int* __restrict__ sums, int n) {
    __shared__ int sm[1024];
    int tid = threadIdx.x;
    int i = blockIdx.x * 1024 + tid;
    int v = (i < n) ? deg[i] : 0;
    sm[tid] = v;
    __syncthreads();
    #pragma unroll
    for (int d = 1; d < 1024; d <<= 1) {
        int t = (tid >= d) ? sm[tid - d] : 0;
        __syncthreads();
        sm[tid] += t;
        __syncthreads();
    }
    if (i < n) off[i] = sm[tid] - v;            // block-local exclusive
    if (tid == 1023) sums[blockIdx.x] = sm[1023];
}

// level 2: exclusive scan of block sums (nb <= 128)
__global__ __launch_bounds__(128) void k_scan2(int* __restrict__ sums, int nb) {
    __shared__ int sm[128];
    int tid = threadIdx.x;
    int v = (tid < nb) ? sums[tid] : 0;
    sm[tid] = v;
    __syncthreads();
    #pragma unroll
    for (int d = 1; d < 128; d <<= 1) {
        int t = (tid >= d) ? sm[tid - d] : 0;
        __syncthreads();
        sm[tid] += t;
        __syncthreads();
    }
    if (tid < nb) sums[tid] = sm[tid] - v;      // exclusive
}

// level 3: add block bases, copy to cursor, write off[n]
__global__ __launch_bounds__(1024) void k_scan3(int* __restrict__ off,
                                                int* __restrict__ cursor,
                                                const int* __restrict__ sums,
                                                int n, int e) {
    int i = blockIdx.x * 1024 + threadIdx.x;
    if (i < n) {
        int o = off[i] + sums[blockIdx.x];
        off[i] = o;
        cursor[i] = o;
    }
    if (i == 0) off[n] = e;
}

__global__ __launch_bounds__(256) void k_fill(const int* __restrict__ src,
                                              const int* __restrict__ dst,
                                              const float* __restrict__ w,
                                              int* __restrict__ cursor,
                                              int* __restrict__ esrc,
                                              float* __restrict__ ew, int e) {
    int i = blockIdx.x * blockDim.x + threadIdx.x;
    if (i < e) {
        int d = dst[i];
        int pos = atomicAdd(&cursor[d], 1);
        esrc[pos] = src[i];
        ew[pos] = w[i];
    }
}

// ---------------- Lorentz linear ----------------
// lane j holds W row j in 16 float4 registers (no LDS for W).
// Each wave processes 16 nodes; p broadcast via conflict-free LDS b128 reads.
// MODE 0: input = x (N x 63), hyperboloid embed first. MODE 1: relu(in) (N x 64).
template <int MODE>
__global__ __launch_bounds__(256) void k_linear(const float* __restrict__ in,
                                                const float* __restrict__ W,
                                                const float* __restrict__ b,
                                                const float* __restrict__ sc,
                                                float* __restrict__ out, int n) {
    __shared__ __align__(16) float4 pbuf[4][16];
    int tid = threadIdx.x;
    int lane = tid & 63, wv = tid >> 6;

    float4 w4[16];
    #pragma unroll
    for (int q = 0; q < 16; ++q)
        w4[q] = *(const float4*)(W + lane * 64 + 4 * q);
    float bj = b[lane];
    float es = expf(sc[0]);

    int node0 = blockIdx.x * 64 + wv * 16;
    int node1 = min(node0 + 16, n);
    for (int node = node0; node < node1; ++node) {
        float p;
        if (MODE == 0) {
            float xv = (lane >= 1) ? in[node * 63 + (lane - 1)] : 0.f;
            float nrm2 = wave_sum64(xv * xv);
            float nrm = fmaxf(sqrtf(nrm2), EPS);
            float sh = sinhf(nrm);
            float ps = (lane == 0) ? 0.f : sh * xv / nrm;
            float sp2 = wave_sum64(ps * ps);
            p = (lane == 0) ? sqrtf(1.f + sp2) : ps;
        } else {
            p = fmaxf(in[node * 64 + lane], 0.f);
        }
        ((float*)&pbuf[wv][0])[lane] = p;   // same-wave LDS: hw keeps ds order

        float acc = bj;
        #pragma unroll
        for (int q = 0; q < 16; ++q) {
            float4 pq = pbuf[wv][q];        // broadcast read, conflict-free
            acc += pq.x * w4[q].x + pq.y * w4[q].y + pq.z * w4[q].z + pq.w * w4[q].w;
        }

        float h0 = __shfl(acc, 0);
        float time = es / (1.f + expf(-h0)) + 1.1f;
        float spv = (lane == 0) ? 0.f : acc;
        float sq = fmaxf(wave_sum64(spv * spv), EPS);
        float r = sqrtf((time * time - 1.f) / sq);
        out[node * 64 + lane] = (lane == 0) ? time : acc * r;
    }
}

// ---------------- Aggregation: one wave per node, lane = dim ----------------
// Edge (src,w) pairs staged in LDS, consumed 2-per-float4-broadcast.
// FINAL 0: out = to_manifold(segsum)
// FINAL 1: h2 = to_manifold(segsum); out = to_manifold(h1 + h2)
template <int FINAL>
__global__ __launch_bounds__(256) void k_agg(const float* __restrict__ t,
                                             const int* __restrict__ off,
                                             const int* __restrict__ esrc,
                                             const float* __restrict__ ew,
                                             const float* __restrict__ h1,
                                             float* __restrict__ out, int n) {
    __shared__ __align__(16) float2 ebuf[4][64];
    int lane = threadIdx.x & 63, wv = threadIdx.x >> 6;
    int node = blockIdx.x * 4 + wv;
    if (node >= n) return;
    int s0 = off[node], s1 = off[node + 1];
    float acc = 0.f;
    for (int base = s0; base < s1; base += 64) {
        int cnt = min(s1 - base, 64);
        if (lane < cnt)
            ebuf[wv][lane] = make_float2(__int_as_float(esrc[base + lane]),
                                         ew[base + lane]);
        int j = 0;
        for (; j + 2 <= cnt; j += 2) {
            float4 e2 = *(const float4*)&ebuf[wv][j];   // broadcast, 2 edges
            int sa = __float_as_int(e2.x);
            int sb = __float_as_int(e2.z);
            acc += e2.y * t[sa * 64 + lane];
            acc += e2.w * t[sb * 64 + lane];
        }
        if (j < cnt) {
            float2 e1 = ebuf[wv][j];
            acc += e1.y * t[__float_as_int(e1.x) * 64 + lane];
        }
    }
    float q = (lane == 0) ? -acc * acc : acc * acc;
    float denom = sqrtf(fmaxf(fabsf(wave_sum64(q)), EPS));
    float h = acc / denom;
    if (FINAL) {
        float v = h1[node * 64 + lane] + h;
        float q2 = (lane == 0) ? -v * v : v * v;
        float denom2 = sqrtf(fmaxf(fabsf(wave_sum64(q2)), EPS));
        out[node * 64 + lane] = v / denom2;
    } else {
        out[node * 64 + lane] = h;
    }
}

extern "C" void kernel_launch(void* const* d_in, const int* in_sizes, int n_in,
                              void* d_out, int out_size, void* d_ws, size_t ws_size,
                              hipStream_t stream) {
    const float* x  = (const float*)d_in[0];
    const int*   ei = (const int*)d_in[1];
    const float* wE = (const float*)d_in[2];
    const float* W1 = (const float*)d_in[3];
    const float* b1 = (const float*)d_in[4];
    const float* s1 = (const float*)d_in[5];
    const float* W2 = (const float*)d_in[6];
    const float* b2 = (const float*)d_in[7];
    const float* s2 = (const float*)d_in[8];
    float* out = (float*)d_out;

    const int N = in_sizes[0] / (D - 1);
    const int E = in_sizes[2];
    const int* src = ei;
    const int* dst = ei + E;

    char* ws = (char*)d_ws;
    float* B1 = (float*)ws;                       // N*64 f32  (t1, then t2)
    float* B2 = B1 + (size_t)N * D;               // N*64 f32  (agg1 -> h1)
    int* off    = (int*)(B2 + (size_t)N * D);     // N+1
    int* cursor = off + (N + 1);                  // N
    int* deg    = cursor + N;                     // N
    int* esrc   = deg + N;                        // E
    float* ew   = (float*)(esrc + E);             // E
    int* sums   = (int*)(ew + E);                 // <=128

    hipMemsetAsync(deg, 0, (size_t)N * sizeof(int), stream);

    int gE = (E + 255) / 256;
    int nb = (N + 1023) / 1024;                   // 79 (<=128)

    k_hist<<<gE, 256, 0, stream>>>(dst, deg, E);
    k_scan1<<<nb, 1024, 0, stream>>>(deg, off, sums, N);
    k_scan2<<<1, 128, 0, stream>>>(sums, nb);
    k_scan3<<<nb, 1024, 0, stream>>>(off, cursor, sums, N, E);
    k_fill<<<gE, 256, 0, stream>>>(src, dst, wE, cursor, esrc, ew, E);

    int gL = (N + 63) / 64;                       // 64 nodes / block
    int gA = (N + 3) / 4;                         // 4 nodes / block

    k_linear<0><<<gL, 256, 0, stream>>>(x, W1, b1, s1, B1, N);
    k_agg<0><<<gA, 256, 0, stream>>>(B1, off, esrc, ew, nullptr, B2, N);
    k_linear<1><<<gL, 256, 0, stream>>>(B2, W2, b2, s2, B1, N);
    k_agg<1><<<gA, 256, 0, stream>>>(B1, off, esrc, ew, B2, out, N);
}

// Round 3
// 360.890 us; speedup vs baseline: 2.2986x; 1.0519x over previous
//
#include <hip/hip_runtime.h>
#include <hip/hip_bf16.h>

#define D 64
#define EPS 1e-8f

__device__ __forceinline__ float wave_sum64(float v) {
    #pragma unroll
    for (int d = 1; d < 64; d <<= 1) v += __shfl_xor(v, d);
    return v;
}

// ---------------- CSR build ----------------
__global__ __launch_bounds__(256) void k_hist(const int* __restrict__ dst,
                                              int* __restrict__ deg, int e) {
    int i = blockIdx.x * blockDim.x + threadIdx.x;
    if (i < e) atomicAdd(&deg[dst[i]], 1);
}

// level 1: per-block exclusive scan (block-local) + block total
__global__ __launch_bounds__(1024) void k_scan1(const int* __restrict__ deg,
                                                int* __restrict__ off,
                                                int* __restrict__ sums, int n) {
    __shared__ int sm[1024];
    int tid = threadIdx.x;
    int i = blockIdx.x * 1024 + tid;
    int v = (i < n) ? deg[i] : 0;
    sm[tid] = v;
    __syncthreads();
    #pragma unroll
    for (int d = 1; d < 1024; d <<= 1) {
        int t = (tid >= d) ? sm[tid - d] : 0;
        __syncthreads();
        sm[tid] += t;
        __syncthreads();
    }
    if (i < n) off[i] = sm[tid] - v;            // block-local exclusive
    if (tid == 1023) sums[blockIdx.x] = sm[1023];
}

// level 2: exclusive scan of block sums (nb <= 128)
__global__ __launch_bounds__(128) void k_scan2(int* __restrict__ sums, int nb) {
    __shared__ int sm[128];
    int tid = threadIdx.x;
    int v = (tid < nb) ? sums[tid] : 0;
    sm[tid] = v;
    __syncthreads();
    #pragma unroll
    for (int d = 1; d < 128; d <<= 1) {
        int t = (tid >= d) ? sm[tid - d] : 0;
        __syncthreads();
        sm[tid] += t;
        __syncthreads();
    }
    if (tid < nb) sums[tid] = sm[tid] - v;      // exclusive
}

// level 3: add block bases, copy to cursor, write off[n]
__global__ __launch_bounds__(1024) void k_scan3(int* __restrict__ off,
                                                int* __restrict__ cursor,
                                                const int* __restrict__ sums,
                                                int n, int e) {
    int i = blockIdx.x * 1024 + threadIdx.x;
    if (i < n) {
        int o = off[i] + sums[blockIdx.x];
        off[i] = o;
        cursor[i] = o;
    }
    if (i == 0) off[n] = e;
}

// scatter (src,w) packed as ONE 8B store per edge -> one line-touch per edge
__global__ __launch_bounds__(256) void k_fill(const int* __restrict__ src,
                                              const int* __restrict__ dst,
                                              const float* __restrict__ w,
                                              int* __restrict__ cursor,
                                              unsigned long long* __restrict__ epack,
                                              int e) {
    int i = blockIdx.x * blockDim.x + threadIdx.x;
    if (i < e) {
        int d = dst[i];
        int pos = atomicAdd(&cursor[d], 1);
        unsigned long long pk = ((unsigned long long)__float_as_uint(w[i]) << 32)
                              | (unsigned int)src[i];
        epack[pos] = pk;
    }
}

// ---------------- Lorentz linear ----------------
// lane j holds W row j in 16 float4 registers (no LDS for W).
// MODE 0: input = x (N x 63), hyperboloid embed first. MODE 1: relu(in) (N x 64).
template <int MODE>
__global__ __launch_bounds__(256) void k_linear(const float* __restrict__ in,
                                                const float* __restrict__ W,
                                                const float* __restrict__ b,
                                                const float* __restrict__ sc,
                                                float* __restrict__ out, int n) {
    __shared__ __align__(16) float4 pbuf[4][16];
    int tid = threadIdx.x;
    int lane = tid & 63, wv = tid >> 6;

    float4 w4[16];
    #pragma unroll
    for (int q = 0; q < 16; ++q)
        w4[q] = *(const float4*)(W + lane * 64 + 4 * q);
    float bj = b[lane];
    float es = expf(sc[0]);

    int node0 = blockIdx.x * 64 + wv * 16;
    int node1 = min(node0 + 16, n);
    for (int node = node0; node < node1; ++node) {
        float p;
        if (MODE == 0) {
            float xv = (lane >= 1) ? in[node * 63 + (lane - 1)] : 0.f;
            float nrm2 = wave_sum64(xv * xv);
            float nrm = fmaxf(sqrtf(nrm2), EPS);
            float sh = sinhf(nrm);
            float ps = (lane == 0) ? 0.f : sh * xv / nrm;
            float sp2 = wave_sum64(ps * ps);
            p = (lane == 0) ? sqrtf(1.f + sp2) : ps;
        } else {
            p = fmaxf(in[node * 64 + lane], 0.f);
        }
        ((float*)&pbuf[wv][0])[lane] = p;   // same-wave LDS: hw keeps ds order

        float acc = bj;
        #pragma unroll
        for (int q = 0; q < 16; ++q) {
            float4 pq = pbuf[wv][q];        // broadcast read, conflict-free
            acc += pq.x * w4[q].x + pq.y * w4[q].y + pq.z * w4[q].z + pq.w * w4[q].w;
        }

        float h0 = __shfl(acc, 0);
        float time = es / (1.f + expf(-h0)) + 1.1f;
        float spv = (lane == 0) ? 0.f : acc;
        float sq = fmaxf(wave_sum64(spv * spv), EPS);
        float r = sqrtf((time * time - 1.f) / sq);
        out[node * 64 + lane] = (lane == 0) ? time : acc * r;
    }
}

// ---------------- Aggregation: one wave per node, lane = dim ----------------
// Edges read coalesced from packed (src,w); 4 edges/iter, 2 accumulators.
// FINAL 0: out = to_manifold(segsum)
// FINAL 1: h2 = to_manifold(segsum); out = to_manifold(h1 + h2)
template <int FINAL>
__global__ __launch_bounds__(256) void k_agg(const float* __restrict__ t,
                                             const int* __restrict__ off,
                                             const float2* __restrict__ epack,
                                             const float* __restrict__ h1,
                                             float* __restrict__ out, int n) {
    __shared__ __align__(16) float2 ebuf[4][64];
    int lane = threadIdx.x & 63, wv = threadIdx.x >> 6;
    int node = blockIdx.x * 4 + wv;
    if (node >= n) return;
    int s0 = off[node], s1 = off[node + 1];
    float acc0 = 0.f, acc1 = 0.f;
    for (int base = s0; base < s1; base += 64) {
        int cnt = min(s1 - base, 64);
        if (lane < cnt)
            ebuf[wv][lane] = epack[base + lane];   // one coalesced 8B read
        int j = 0;
        for (; j + 4 <= cnt; j += 4) {
            float4 a = *(const float4*)&ebuf[wv][j];       // 2 edges
            float4 c = *(const float4*)&ebuf[wv][j + 2];   // 2 edges
            acc0 += a.y * t[__float_as_int(a.x) * 64 + lane];
            acc1 += a.w * t[__float_as_int(a.z) * 64 + lane];
            acc0 += c.y * t[__float_as_int(c.x) * 64 + lane];
            acc1 += c.w * t[__float_as_int(c.z) * 64 + lane];
        }
        for (; j < cnt; ++j) {
            float2 e1 = ebuf[wv][j];
            acc0 += e1.y * t[__float_as_int(e1.x) * 64 + lane];
        }
    }
    float acc = acc0 + acc1;
    float q = (lane == 0) ? -acc * acc : acc * acc;
    float denom = sqrtf(fmaxf(fabsf(wave_sum64(q)), EPS));
    float h = acc / denom;
    if (FINAL) {
        float v = h1[node * 64 + lane] + h;
        float q2 = (lane == 0) ? -v * v : v * v;
        float denom2 = sqrtf(fmaxf(fabsf(wave_sum64(q2)), EPS));
        out[node * 64 + lane] = v / denom2;
    } else {
        out[node * 64 + lane] = h;
    }
}

extern "C" void kernel_launch(void* const* d_in, const int* in_sizes, int n_in,
                              void* d_out, int out_size, void* d_ws, size_t ws_size,
                              hipStream_t stream) {
    const float* x  = (const float*)d_in[0];
    const int*   ei = (const int*)d_in[1];
    const float* wE = (const float*)d_in[2];
    const float* W1 = (const float*)d_in[3];
    const float* b1 = (const float*)d_in[4];
    const float* s1 = (const float*)d_in[5];
    const float* W2 = (const float*)d_in[6];
    const float* b2 = (const float*)d_in[7];
    const float* s2 = (const float*)d_in[8];
    float* out = (float*)d_out;

    const int N = in_sizes[0] / (D - 1);
    const int E = in_sizes[2];
    const int* src = ei;
    const int* dst = ei + E;

    char* ws = (char*)d_ws;
    float* B1 = (float*)ws;                       // N*64 f32  (t1, then t2)
    float* B2 = B1 + (size_t)N * D;               // N*64 f32  (agg1 -> h1)
    int* off    = (int*)(B2 + (size_t)N * D);     // N+1
    int* cursor = off + (N + 1);                  // N
    int* deg    = cursor + N;                     // N
    unsigned long long* epack = (unsigned long long*)(deg + N + 1); // E x 8B
    int* sums   = (int*)(epack + E);              // <=128

    hipMemsetAsync(deg, 0, (size_t)N * sizeof(int), stream);

    int gE = (E + 255) / 256;
    int nb = (N + 1023) / 1024;                   // 79 (<=128)

    k_hist<<<gE, 256, 0, stream>>>(dst, deg, E);
    k_scan1<<<nb, 1024, 0, stream>>>(deg, off, sums, N);
    k_scan2<<<1, 128, 0, stream>>>(sums, nb);
    k_scan3<<<nb, 1024, 0, stream>>>(off, cursor, sums, N, E);
    k_fill<<<gE, 256, 0, stream>>>(src, dst, wE, cursor, epack, E);

    int gL = (N + 63) / 64;                       // 64 nodes / block
    int gA = (N + 3) / 4;                         // 4 nodes / block

    k_linear<0><<<gL, 256, 0, stream>>>(x, W1, b1, s1, B1, N);
    k_agg<0><<<gA, 256, 0, stream>>>(B1, off, (const float2*)epack, nullptr, B2, N);
    k_linear<1><<<gL, 256, 0, stream>>>(B2, W2, b2, s2, B1, N);
    k_agg<1><<<gA, 256, 0, stream>>>(B1, off, (const float2*)epack, B2, out, N);
}

// Round 4
// 359.830 us; speedup vs baseline: 2.3054x; 1.0029x over previous
//
#include <hip/hip_runtime.h>
#include <hip/hip_bf16.h>

#define D 64
#define EPS 1e-8f

__device__ __forceinline__ float wave_sum64(float v) {
    #pragma unroll
    for (int d = 1; d < 64; d <<= 1) v += __shfl_xor(v, d);
    return v;
}

// ---------------- CSR build ----------------
__global__ __launch_bounds__(256) void k_hist(const int* __restrict__ dst,
                                              int* __restrict__ deg, int e) {
    int base = blockIdx.x * 1024 + threadIdx.x;
    #pragma unroll
    for (int u = 0; u < 4; ++u) {
        int i = base + u * 256;
        if (i < e) atomicAdd(&deg[dst[i]], 1);
    }
}

// level 1: per-block exclusive scan (block-local) + block total
__global__ __launch_bounds__(1024) void k_scan1(const int* __restrict__ deg,
                                                int* __restrict__ off,
                                                int* __restrict__ sums, int n) {
    __shared__ int sm[1024];
    int tid = threadIdx.x;
    int i = blockIdx.x * 1024 + tid;
    int v = (i < n) ? deg[i] : 0;
    sm[tid] = v;
    __syncthreads();
    #pragma unroll
    for (int d = 1; d < 1024; d <<= 1) {
        int t = (tid >= d) ? sm[tid - d] : 0;
        __syncthreads();
        sm[tid] += t;
        __syncthreads();
    }
    if (i < n) off[i] = sm[tid] - v;            // block-local exclusive
    if (tid == 1023) sums[blockIdx.x] = sm[1023];
}

// level 2: exclusive scan of block sums (nb <= 128)
__global__ __launch_bounds__(128) void k_scan2(int* __restrict__ sums, int nb) {
    __shared__ int sm[128];
    int tid = threadIdx.x;
    int v = (tid < nb) ? sums[tid] : 0;
    sm[tid] = v;
    __syncthreads();
    #pragma unroll
    for (int d = 1; d < 128; d <<= 1) {
        int t = (tid >= d) ? sm[tid - d] : 0;
        __syncthreads();
        sm[tid] += t;
        __syncthreads();
    }
    if (tid < nb) sums[tid] = sm[tid] - v;      // exclusive
}

// level 3: add block bases, copy to cursor, write off[n]
__global__ __launch_bounds__(1024) void k_scan3(int* __restrict__ off,
                                                int* __restrict__ cursor,
                                                const int* __restrict__ sums,
                                                int n, int e) {
    int i = blockIdx.x * 1024 + threadIdx.x;
    if (i < n) {
        int o = off[i] + sums[blockIdx.x];
        off[i] = o;
        cursor[i] = o;
    }
    if (i == 0) off[n] = e;
}

// scatter (src,w) as ONE nontemporal 8B store per edge; 4 edges/thread for MLP
__global__ __launch_bounds__(256) void k_fill(const int* __restrict__ src,
                                              const int* __restrict__ dst,
                                              const float* __restrict__ w,
                                              int* __restrict__ cursor,
                                              unsigned long long* __restrict__ epack,
                                              int e) {
    int base = blockIdx.x * 1024 + threadIdx.x;
    int idx[4]; int pos[4];
    #pragma unroll
    for (int u = 0; u < 4; ++u) {
        int i = base + u * 256;
        idx[u] = i;
        if (i < e) pos[u] = atomicAdd(&cursor[dst[i]], 1);
    }
    #pragma unroll
    for (int u = 0; u < 4; ++u) {
        int i = idx[u];
        if (i < e) {
            unsigned long long pk =
                ((unsigned long long)__float_as_uint(w[i]) << 32) | (unsigned int)src[i];
            __builtin_nontemporal_store(pk, &epack[pos[u]]);
        }
    }
}

// ---------------- Lorentz linear ----------------
// lane j holds W row j in 16 float4 registers (no LDS for W).
// MODE 0: input = x (N x 63), hyperboloid embed first. MODE 1: relu(in) (N x 64).
template <int MODE>
__global__ __launch_bounds__(256) void k_linear(const float* __restrict__ in,
                                                const float* __restrict__ W,
                                                const float* __restrict__ b,
                                                const float* __restrict__ sc,
                                                float* __restrict__ out, int n) {
    __shared__ __align__(16) float4 pbuf[4][16];
    int tid = threadIdx.x;
    int lane = tid & 63, wv = tid >> 6;

    float4 w4[16];
    #pragma unroll
    for (int q = 0; q < 16; ++q)
        w4[q] = *(const float4*)(W + lane * 64 + 4 * q);
    float bj = b[lane];
    float es = expf(sc[0]);

    int node0 = blockIdx.x * 64 + wv * 16;
    int node1 = min(node0 + 16, n);
    for (int node = node0; node < node1; ++node) {
        float p;
        if (MODE == 0) {
            float xv = (lane >= 1) ? in[node * 63 + (lane - 1)] : 0.f;
            float nrm2 = wave_sum64(xv * xv);
            float nrm = fmaxf(sqrtf(nrm2), EPS);
            float sh = sinhf(nrm);
            float ps = (lane == 0) ? 0.f : sh * xv / nrm;
            float sp2 = wave_sum64(ps * ps);
            p = (lane == 0) ? sqrtf(1.f + sp2) : ps;
        } else {
            p = fmaxf(in[node * 64 + lane], 0.f);
        }
        ((float*)&pbuf[wv][0])[lane] = p;   // same-wave LDS: hw keeps ds order

        float acc = bj;
        #pragma unroll
        for (int q = 0; q < 16; ++q) {
            float4 pq = pbuf[wv][q];        // broadcast read, conflict-free
            acc += pq.x * w4[q].x + pq.y * w4[q].y + pq.z * w4[q].z + pq.w * w4[q].w;
        }

        float h0 = __shfl(acc, 0);
        float time = es / (1.f + expf(-h0)) + 1.1f;
        float spv = (lane == 0) ? 0.f : acc;
        float sq = fmaxf(wave_sum64(spv * spv), EPS);
        float r = sqrtf((time * time - 1.f) / sq);
        float o = (lane == 0) ? time : acc * r;
        __builtin_nontemporal_store(o, &out[node * 64 + lane]);
    }
}

// ---------------- Aggregation: one wave per node, lane = dim ----------------
// Edges read coalesced from packed (src,w); 8 edges/iter, 4 accumulators.
// FINAL 0: out = to_manifold(segsum)
// FINAL 1: h2 = to_manifold(segsum); out = to_manifold(h1 + h2)
template <int FINAL>
__global__ __launch_bounds__(256) void k_agg(const float* __restrict__ t,
                                             const int* __restrict__ off,
                                             const float2* __restrict__ epack,
                                             const float* __restrict__ h1,
                                             float* __restrict__ out, int n) {
    __shared__ __align__(16) float2 ebuf[4][64];
    int lane = threadIdx.x & 63, wv = threadIdx.x >> 6;
    int node = blockIdx.x * 4 + wv;
    if (node >= n) return;
    int s0 = off[node], s1 = off[node + 1];
    float acc0 = 0.f, acc1 = 0.f, acc2 = 0.f, acc3 = 0.f;
    for (int base = s0; base < s1; base += 64) {
        int cnt = min(s1 - base, 64);
        if (lane < cnt)
            ebuf[wv][lane] = epack[base + lane];   // one coalesced 8B read
        int j = 0;
        for (; j + 8 <= cnt; j += 8) {
            float4 a = *(const float4*)&ebuf[wv][j];
            float4 c = *(const float4*)&ebuf[wv][j + 2];
            float4 e = *(const float4*)&ebuf[wv][j + 4];
            float4 g = *(const float4*)&ebuf[wv][j + 6];
            acc0 += a.y * t[__float_as_int(a.x) * 64 + lane];
            acc1 += a.w * t[__float_as_int(a.z) * 64 + lane];
            acc2 += c.y * t[__float_as_int(c.x) * 64 + lane];
            acc3 += c.w * t[__float_as_int(c.z) * 64 + lane];
            acc0 += e.y * t[__float_as_int(e.x) * 64 + lane];
            acc1 += e.w * t[__float_as_int(e.z) * 64 + lane];
            acc2 += g.y * t[__float_as_int(g.x) * 64 + lane];
            acc3 += g.w * t[__float_as_int(g.z) * 64 + lane];
        }
        for (; j + 2 <= cnt; j += 2) {
            float4 a = *(const float4*)&ebuf[wv][j];
            acc0 += a.y * t[__float_as_int(a.x) * 64 + lane];
            acc1 += a.w * t[__float_as_int(a.z) * 64 + lane];
        }
        if (j < cnt) {
            float2 e1 = ebuf[wv][j];
            acc0 += e1.y * t[__float_as_int(e1.x) * 64 + lane];
        }
    }
    float acc = (acc0 + acc1) + (acc2 + acc3);
    float q = (lane == 0) ? -acc * acc : acc * acc;
    float denom = sqrtf(fmaxf(fabsf(wave_sum64(q)), EPS));
    float h = acc / denom;
    if (FINAL) {
        float v = h1[node * 64 + lane] + h;
        float q2 = (lane == 0) ? -v * v : v * v;
        float denom2 = sqrtf(fmaxf(fabsf(wave_sum64(q2)), EPS));
        __builtin_nontemporal_store(v / denom2, &out[node * 64 + lane]);
    } else {
        __builtin_nontemporal_store(h, &out[node * 64 + lane]);
    }
}

extern "C" void kernel_launch(void* const* d_in, const int* in_sizes, int n_in,
                              void* d_out, int out_size, void* d_ws, size_t ws_size,
                              hipStream_t stream) {
    const float* x  = (const float*)d_in[0];
    const int*   ei = (const int*)d_in[1];
    const float* wE = (const float*)d_in[2];
    const float* W1 = (const float*)d_in[3];
    const float* b1 = (const float*)d_in[4];
    const float* s1 = (const float*)d_in[5];
    const float* W2 = (const float*)d_in[6];
    const float* b2 = (const float*)d_in[7];
    const float* s2 = (const float*)d_in[8];
    float* out = (float*)d_out;

    const int N = in_sizes[0] / (D - 1);
    const int E = in_sizes[2];
    const int* src = ei;
    const int* dst = ei + E;

    char* ws = (char*)d_ws;
    float* B1 = (float*)ws;                       // N*64 f32  (t1, then t2)
    float* B2 = B1 + (size_t)N * D;               // N*64 f32  (agg1 -> h1)
    int* off    = (int*)(B2 + (size_t)N * D);     // N+1
    int* cursor = off + (N + 1);                  // N
    int* deg    = cursor + N;                     // N
    unsigned long long* epack = (unsigned long long*)(deg + N + 1); // E x 8B
    int* sums   = (int*)(epack + E);              // <=128

    hipMemsetAsync(deg, 0, (size_t)N * sizeof(int), stream);

    int gE4 = (E + 1023) / 1024;
    int nb = (N + 1023) / 1024;                   // 79 (<=128)

    k_hist<<<gE4, 256, 0, stream>>>(dst, deg, E);
    k_scan1<<<nb, 1024, 0, stream>>>(deg, off, sums, N);
    k_scan2<<<1, 128, 0, stream>>>(sums, nb);
    k_scan3<<<nb, 1024, 0, stream>>>(off, cursor, sums, N, E);
    k_fill<<<gE4, 256, 0, stream>>>(src, dst, wE, cursor, epack, E);

    int gL = (N + 63) / 64;                       // 64 nodes / block
    int gA = (N + 3) / 4;                         // 4 nodes / block

    k_linear<0><<<gL, 256, 0, stream>>>(x, W1, b1, s1, B1, N);
    k_agg<0><<<gA, 256, 0, stream>>>(B1, off, (const float2*)epack, nullptr, B2, N);
    k_linear<1><<<gL, 256, 0, stream>>>(B2, W2, b2, s2, B1, N);
    k_agg<1><<<gA, 256, 0, stream>>>(B1, off, (const float2*)epack, B2, out, N);
}

// Round 5
// 337.680 us; speedup vs baseline: 2.4566x; 1.0656x over previous
//
#include <hip/hip_runtime.h>
#include <hip/hip_bf16.h>

#define D 64
#define EPS 1e-8f
#define BSH 10                         // nodes per bucket = 1024
#define BNODES (1 << BSH)

__device__ __forceinline__ float wave_sum64(float v) {
    #pragma unroll
    for (int d = 1; d < 64; d <<= 1) v += __shfl_xor(v, d);
    return v;
}

// ---------------- CSR build ----------------
__global__ __launch_bounds__(256) void k_hist(const int* __restrict__ dst,
                                              int* __restrict__ deg, int e) {
    int base = blockIdx.x * 1024 + threadIdx.x;
    #pragma unroll
    for (int u = 0; u < 4; ++u) {
        int i = base + u * 256;
        if (i < e) atomicAdd(&deg[dst[i]], 1);
    }
}

__global__ __launch_bounds__(1024) void k_scan1(const int* __restrict__ deg,
                                                int* __restrict__ off,
                                                int* __restrict__ sums, int n) {
    __shared__ int sm[1024];
    int tid = threadIdx.x;
    int i = blockIdx.x * 1024 + tid;
    int v = (i < n) ? deg[i] : 0;
    sm[tid] = v;
    __syncthreads();
    #pragma unroll
    for (int d = 1; d < 1024; d <<= 1) {
        int t = (tid >= d) ? sm[tid - d] : 0;
        __syncthreads();
        sm[tid] += t;
        __syncthreads();
    }
    if (i < n) off[i] = sm[tid] - v;
    if (tid == 1023) sums[blockIdx.x] = sm[1023];
}

__global__ __launch_bounds__(128) void k_scan2(int* __restrict__ sums, int nb) {
    __shared__ int sm[128];
    int tid = threadIdx.x;
    int v = (tid < nb) ? sums[tid] : 0;
    sm[tid] = v;
    __syncthreads();
    #pragma unroll
    for (int d = 1; d < 128; d <<= 1) {
        int t = (tid >= d) ? sm[tid - d] : 0;
        __syncthreads();
        sm[tid] += t;
        __syncthreads();
    }
    if (tid < nb) sums[tid] = sm[tid] - v;
}

__global__ __launch_bounds__(1024) void k_scan3(int* __restrict__ off,
                                                const int* __restrict__ sums,
                                                int n, int e) {
    int i = blockIdx.x * 1024 + threadIdx.x;
    if (i < n) off[i] += sums[blockIdx.x];
    if (i == 0) off[n] = e;
}

// gcur[b] = start of bucket b's CSR range
__global__ __launch_bounds__(128) void k_binit(const int* __restrict__ off,
                                               int* __restrict__ gcur,
                                               int n, int nbuck) {
    int b = threadIdx.x;
    if (b < nbuck) gcur[b] = off[min(b << BSH, n)];
}

// ---- Pass A: bucket edges by dst>>BSH; contiguous per-(block,bucket) runs ----
// pack: [w:32][dstlow:10 @bit20][src:20]
__global__ __launch_bounds__(256) void k_bucketA(const int* __restrict__ src,
                                                 const int* __restrict__ dst,
                                                 const float* __restrict__ w,
                                                 int* __restrict__ gcur,
                                                 unsigned long long* __restrict__ tmp,
                                                 int e, int nbuck) {
    __shared__ int cnt[128];
    __shared__ int base[128];
    int tid = threadIdx.x;
    for (int b = tid; b < nbuck; b += 256) cnt[b] = 0;
    __syncthreads();
    int i0 = blockIdx.x * 1024 + tid;
    int bkt[4], rnk[4];
    #pragma unroll
    for (int u = 0; u < 4; ++u) {
        int i = i0 + u * 256;
        if (i < e) {
            int b = dst[i] >> BSH;
            bkt[u] = b;
            rnk[u] = atomicAdd(&cnt[b], 1);
        }
    }
    __syncthreads();
    for (int b = tid; b < nbuck; b += 256) {
        int c = cnt[b];
        base[b] = c ? atomicAdd(&gcur[b], c) : 0;
    }
    __syncthreads();
    #pragma unroll
    for (int u = 0; u < 4; ++u) {
        int i = i0 + u * 256;
        if (i < e) {
            unsigned long long pk =
                ((unsigned long long)__float_as_uint(w[i]) << 32)
                | (unsigned int)(src[i] | ((dst[i] & (BNODES - 1)) << 20));
            tmp[base[bkt[u]] + rnk[u]] = pk;
        }
    }
}

// ---- Pass B: within-bucket scatter to exact CSR slot; LDS cursors ----
__global__ __launch_bounds__(1024) void k_bucketB(const unsigned long long* __restrict__ tmp,
                                                  const int* __restrict__ off,
                                                  unsigned long long* __restrict__ epack,
                                                  int n) {
    __shared__ int cur[BNODES];
    int b = blockIdx.x;
    int v0 = b << BSH;
    int nv = min(BNODES, n - v0);
    int tid = threadIdx.x;
    for (int v = tid; v < nv; v += 1024) cur[v] = off[v0 + v];
    __syncthreads();
    int s0 = off[v0];
    int s1 = off[min(v0 + BNODES, n)];
    for (int i = s0 + tid; i < s1; i += 1024) {
        unsigned long long pk = tmp[i];
        int dl = ((unsigned int)pk >> 20) & (BNODES - 1);
        int pos = atomicAdd(&cur[dl], 1);
        epack[pos] = pk & 0xFFFFFFFFC00FFFFFULL;   // clear dstlow bits
    }
}

// ---------------- Lorentz linear ----------------
template <int MODE>
__global__ __launch_bounds__(256) void k_linear(const float* __restrict__ in,
                                                const float* __restrict__ W,
                                                const float* __restrict__ b,
                                                const float* __restrict__ sc,
                                                float* __restrict__ out, int n) {
    __shared__ __align__(16) float4 pbuf[4][16];
    int tid = threadIdx.x;
    int lane = tid & 63, wv = tid >> 6;

    float4 w4[16];
    #pragma unroll
    for (int q = 0; q < 16; ++q)
        w4[q] = *(const float4*)(W + lane * 64 + 4 * q);
    float bj = b[lane];
    float es = expf(sc[0]);

    int node0 = blockIdx.x * 64 + wv * 16;
    int node1 = min(node0 + 16, n);
    for (int node = node0; node < node1; ++node) {
        float p;
        if (MODE == 0) {
            float xv = (lane >= 1) ? in[node * 63 + (lane - 1)] : 0.f;
            float nrm2 = wave_sum64(xv * xv);
            float nrm = fmaxf(sqrtf(nrm2), EPS);
            float sh = sinhf(nrm);
            float ps = (lane == 0) ? 0.f : sh * xv / nrm;
            float sp2 = wave_sum64(ps * ps);
            p = (lane == 0) ? sqrtf(1.f + sp2) : ps;
        } else {
            p = fmaxf(in[node * 64 + lane], 0.f);
        }
        ((float*)&pbuf[wv][0])[lane] = p;

        float acc = bj;
        #pragma unroll
        for (int q = 0; q < 16; ++q) {
            float4 pq = pbuf[wv][q];
            acc += pq.x * w4[q].x + pq.y * w4[q].y + pq.z * w4[q].z + pq.w * w4[q].w;
        }

        float h0 = __shfl(acc, 0);
        float time = es / (1.f + expf(-h0)) + 1.1f;
        float spv = (lane == 0) ? 0.f : acc;
        float sq = fmaxf(wave_sum64(spv * spv), EPS);
        float r = sqrtf((time * time - 1.f) / sq);
        // normal store: this array is the gather TABLE for the next agg (keep in L2)
        out[node * 64 + lane] = (lane == 0) ? time : acc * r;
    }
}

// ---------------- Aggregation ----------------
template <int FINAL>
__global__ __launch_bounds__(256) void k_agg(const float* __restrict__ t,
                                             const int* __restrict__ off,
                                             const float2* __restrict__ epack,
                                             const float* __restrict__ h1,
                                             float* __restrict__ out, int n) {
    __shared__ __align__(16) float2 ebuf[4][64];
    int lane = threadIdx.x & 63, wv = threadIdx.x >> 6;
    int node = blockIdx.x * 4 + wv;
    if (node >= n) return;
    int s0 = off[node], s1 = off[node + 1];
    float acc0 = 0.f, acc1 = 0.f, acc2 = 0.f, acc3 = 0.f;
    for (int base = s0; base < s1; base += 64) {
        int cnt = min(s1 - base, 64);
        if (lane < cnt)
            ebuf[wv][lane] = epack[base + lane];
        int j = 0;
        for (; j + 8 <= cnt; j += 8) {
            float4 a = *(const float4*)&ebuf[wv][j];
            float4 c = *(const float4*)&ebuf[wv][j + 2];
            float4 e = *(const float4*)&ebuf[wv][j + 4];
            float4 g = *(const float4*)&ebuf[wv][j + 6];
            acc0 += a.y * t[__float_as_int(a.x) * 64 + lane];
            acc1 += a.w * t[__float_as_int(a.z) * 64 + lane];
            acc2 += c.y * t[__float_as_int(c.x) * 64 + lane];
            acc3 += c.w * t[__float_as_int(c.z) * 64 + lane];
            acc0 += e.y * t[__float_as_int(e.x) * 64 + lane];
            acc1 += e.w * t[__float_as_int(e.z) * 64 + lane];
            acc2 += g.y * t[__float_as_int(g.x) * 64 + lane];
            acc3 += g.w * t[__float_as_int(g.z) * 64 + lane];
        }
        for (; j + 2 <= cnt; j += 2) {
            float4 a = *(const float4*)&ebuf[wv][j];
            acc0 += a.y * t[__float_as_int(a.x) * 64 + lane];
            acc1 += a.w * t[__float_as_int(a.z) * 64 + lane];
        }
        if (j < cnt) {
            float2 e1 = ebuf[wv][j];
            acc0 += e1.y * t[__float_as_int(e1.x) * 64 + lane];
        }
    }
    float acc = (acc0 + acc1) + (acc2 + acc3);
    float q = (lane == 0) ? -acc * acc : acc * acc;
    float denom = sqrtf(fmaxf(fabsf(wave_sum64(q)), EPS));
    float h = acc / denom;
    if (FINAL) {
        float v = h1[node * 64 + lane] + h;
        float q2 = (lane == 0) ? -v * v : v * v;
        float denom2 = sqrtf(fmaxf(fabsf(wave_sum64(q2)), EPS));
        __builtin_nontemporal_store(v / denom2, &out[node * 64 + lane]);
    } else {
        __builtin_nontemporal_store(h, &out[node * 64 + lane]);
    }
}

extern "C" void kernel_launch(void* const* d_in, const int* in_sizes, int n_in,
                              void* d_out, int out_size, void* d_ws, size_t ws_size,
                              hipStream_t stream) {
    const float* x  = (const float*)d_in[0];
    const int*   ei = (const int*)d_in[1];
    const float* wE = (const float*)d_in[2];
    const float* W1 = (const float*)d_in[3];
    const float* b1 = (const float*)d_in[4];
    const float* s1 = (const float*)d_in[5];
    const float* W2 = (const float*)d_in[6];
    const float* b2 = (const float*)d_in[7];
    const float* s2 = (const float*)d_in[8];
    float* out = (float*)d_out;

    const int N = in_sizes[0] / (D - 1);
    const int E = in_sizes[2];
    const int* src = ei;
    const int* dst = ei + E;
    const int nbuck = (N + BNODES - 1) >> BSH;    // 79

    char* ws = (char*)d_ws;
    float* B1 = (float*)ws;                                   // N*64 f32 (table; reused as tmp)
    float* B2 = B1 + (size_t)N * D;                           // N*64 f32
    unsigned long long* epack = (unsigned long long*)(B2 + (size_t)N * D); // E x 8B
    int* off  = (int*)(epack + E);                            // N+1
    int* deg  = off + (N + 1);                                // N
    int* gcur = deg + N;                                      // nbuck
    int* sums = gcur + 128;                                   // <=128
    unsigned long long* tmp = (unsigned long long*)B1;        // E x 8B (pre-linear phase)

    hipMemsetAsync(deg, 0, (size_t)N * sizeof(int), stream);

    int gE4 = (E + 1023) / 1024;
    int nb = (N + 1023) / 1024;

    k_hist<<<gE4, 256, 0, stream>>>(dst, deg, E);
    k_scan1<<<nb, 1024, 0, stream>>>(deg, off, sums, N);
    k_scan2<<<1, 128, 0, stream>>>(sums, nb);
    k_scan3<<<nb, 1024, 0, stream>>>(off, sums, N, E);
    k_binit<<<1, 128, 0, stream>>>(off, gcur, N, nbuck);
    k_bucketA<<<gE4, 256, 0, stream>>>(src, dst, wE, gcur, tmp, E, nbuck);
    k_bucketB<<<nbuck, 1024, 0, stream>>>(tmp, off, epack, N);

    int gL = (N + 63) / 64;
    int gA = (N + 3) / 4;

    k_linear<0><<<gL, 256, 0, stream>>>(x, W1, b1, s1, B1, N);
    k_agg<0><<<gA, 256, 0, stream>>>(B1, off, (const float2*)epack, nullptr, B2, N);
    k_linear<1><<<gL, 256, 0, stream>>>(B2, W2, b2, s2, B1, N);
    k_agg<1><<<gA, 256, 0, stream>>>(B1, off, (const float2*)epack, B2, out, N);
}

// Round 6
// 289.091 us; speedup vs baseline: 2.8695x; 1.1681x over previous
//
#include <hip/hip_runtime.h>
#include <hip/hip_bf16.h>

#define D 64
#define EPS 1e-8f
#define BSH 10                         // nodes per bucket = 1024
#define BNODES (1 << BSH)

typedef __attribute__((ext_vector_type(8))) short bf16x8;
typedef __attribute__((ext_vector_type(4))) float f32x4;

__device__ __forceinline__ float wave_sum64(float v) {
    #pragma unroll
    for (int d = 1; d < 64; d <<= 1) v += __shfl_xor(v, d);
    return v;
}

// split 8 f32 into hi/lo bf16 (truncation; hi+lo carries ~16 mantissa bits)
__device__ __forceinline__ void split8(float4 a, float4 b, bf16x8& h, bf16x8& l) {
    float f[8] = {a.x, a.y, a.z, a.w, b.x, b.y, b.z, b.w};
    #pragma unroll
    for (int i = 0; i < 8; ++i) {
        unsigned u = __float_as_uint(f[i]);
        float hf = __uint_as_float(u & 0xFFFF0000u);
        unsigned lu = __float_as_uint(f[i] - hf);
        h[i] = (short)(u >> 16);
        l[i] = (short)(lu >> 16);
    }
}

// ---------------- CSR build ----------------
__global__ __launch_bounds__(256) void k_hist(const int* __restrict__ dst,
                                              int* __restrict__ deg, int e) {
    int base = blockIdx.x * 1024 + threadIdx.x;
    #pragma unroll
    for (int u = 0; u < 4; ++u) {
        int i = base + u * 256;
        if (i < e) atomicAdd(&deg[dst[i]], 1);
    }
}

__global__ __launch_bounds__(1024) void k_scan1(const int* __restrict__ deg,
                                                int* __restrict__ off,
                                                int* __restrict__ sums, int n) {
    __shared__ int sm[1024];
    int tid = threadIdx.x;
    int i = blockIdx.x * 1024 + tid;
    int v = (i < n) ? deg[i] : 0;
    sm[tid] = v;
    __syncthreads();
    #pragma unroll
    for (int d = 1; d < 1024; d <<= 1) {
        int t = (tid >= d) ? sm[tid - d] : 0;
        __syncthreads();
        sm[tid] += t;
        __syncthreads();
    }
    if (i < n) off[i] = sm[tid] - v;
    if (tid == 1023) sums[blockIdx.x] = sm[1023];
}

__global__ __launch_bounds__(128) void k_scan2(int* __restrict__ sums, int nb) {
    __shared__ int sm[128];
    int tid = threadIdx.x;
    int v = (tid < nb) ? sums[tid] : 0;
    sm[tid] = v;
    __syncthreads();
    #pragma unroll
    for (int d = 1; d < 128; d <<= 1) {
        int t = (tid >= d) ? sm[tid - d] : 0;
        __syncthreads();
        sm[tid] += t;
        __syncthreads();
    }
    if (tid < nb) sums[tid] = sm[tid] - v;
}

__global__ __launch_bounds__(1024) void k_scan3(int* __restrict__ off,
                                                const int* __restrict__ sums,
                                                int n, int e) {
    int i = blockIdx.x * 1024 + threadIdx.x;
    if (i < n) off[i] += sums[blockIdx.x];
    if (i == 0) off[n] = e;
}

__global__ __launch_bounds__(128) void k_binit(const int* __restrict__ off,
                                               int* __restrict__ gcur,
                                               int n, int nbuck) {
    int b = threadIdx.x;
    if (b < nbuck) gcur[b] = off[min(b << BSH, n)];
}

// ---- Pass A: bucket edges by dst>>BSH; pack [w:32][dstlow:10 @20][src:20] ----
__global__ __launch_bounds__(256) void k_bucketA(const int* __restrict__ src,
                                                 const int* __restrict__ dst,
                                                 const float* __restrict__ w,
                                                 int* __restrict__ gcur,
                                                 unsigned long long* __restrict__ tmp,
                                                 int e, int nbuck) {
    __shared__ int cnt[128];
    __shared__ int base[128];
    int tid = threadIdx.x;
    for (int b = tid; b < nbuck; b += 256) cnt[b] = 0;
    __syncthreads();
    int i0 = blockIdx.x * 1024 + tid;
    int bkt[4], rnk[4];
    #pragma unroll
    for (int u = 0; u < 4; ++u) {
        int i = i0 + u * 256;
        if (i < e) {
            int b = dst[i] >> BSH;
            bkt[u] = b;
            rnk[u] = atomicAdd(&cnt[b], 1);
        }
    }
    __syncthreads();
    for (int b = tid; b < nbuck; b += 256) {
        int c = cnt[b];
        base[b] = c ? atomicAdd(&gcur[b], c) : 0;
    }
    __syncthreads();
    #pragma unroll
    for (int u = 0; u < 4; ++u) {
        int i = i0 + u * 256;
        if (i < e) {
            unsigned long long pk =
                ((unsigned long long)__float_as_uint(w[i]) << 32)
                | (unsigned int)(src[i] | ((dst[i] & (BNODES - 1)) << 20));
            tmp[base[bkt[u]] + rnk[u]] = pk;
        }
    }
}

// ---- Pass B: within-bucket scatter; LDS cursors ----
__global__ __launch_bounds__(1024) void k_bucketB(const unsigned long long* __restrict__ tmp,
                                                  const int* __restrict__ off,
                                                  unsigned long long* __restrict__ epack,
                                                  int n) {
    __shared__ int cur[BNODES];
    int b = blockIdx.x;
    int v0 = b << BSH;
    int nv = min(BNODES, n - v0);
    int tid = threadIdx.x;
    for (int v = tid; v < nv; v += 1024) cur[v] = off[v0 + v];
    __syncthreads();
    int s0 = off[v0];
    int s1 = off[min(v0 + BNODES, n)];
    for (int i = s0 + tid; i < s1; i += 1024) {
        unsigned long long pk = tmp[i];
        int dl = ((unsigned int)pk >> 20) & (BNODES - 1);
        int pos = atomicAdd(&cur[dl], 1);
        epack[pos] = pk & 0xFFFFFFFFC00FFFFFULL;
    }
}

// ---------------- Hyperboloid embed: x(N x 63) -> P(N x 64) ----------------
__global__ __launch_bounds__(256) void k_embed(const float* __restrict__ x,
                                               float* __restrict__ P, int n) {
    int lane = threadIdx.x & 63, wv = threadIdx.x >> 6;
    int node0 = blockIdx.x * 64 + wv * 16;
    int node1 = min(node0 + 16, n);
    for (int node = node0; node < node1; ++node) {
        float xv = (lane >= 1) ? x[(size_t)node * 63 + (lane - 1)] : 0.f;
        float nrm2 = wave_sum64(xv * xv);
        float nrm = fmaxf(sqrtf(nrm2), EPS);
        float sh = sinhf(nrm);
        float ps = sh * xv / nrm;               // lane0: 0
        float pt = sqrtf(1.f + sh * sh);
        P[(size_t)node * 64 + lane] = (lane == 0) ? pt : ps;
    }
}

// ---------------- Lorentz linear via split-bf16 MFMA ----------------
// C[16n x 64] = A @ W^T + b, epilogue fused. Wave = 16 nodes.
// A-frag: row=lane&15, k=(lane>>4)*8+e.  B-frag: col=lane&15, k=(lane>>4)*8+e
// (B[k][j]=W[j][k] -> lane reads W row (t*16+col), 8 contiguous k).
// C/D: col=lane&15, row=(lane>>4)*4+reg  [HW-verified mapping].
template <int RELU>
__global__ __launch_bounds__(256) void k_lin_mfma(const float* __restrict__ tbl,
                                                  const float* __restrict__ W,
                                                  const float* __restrict__ bias,
                                                  const float* __restrict__ sc,
                                                  float* __restrict__ out, int n) {
    int lane = threadIdx.x & 63, wv = threadIdx.x >> 6;
    int col = lane & 15, grp = lane >> 4;
    int node0 = blockIdx.x * 64 + wv * 16;
    if (node0 >= n) return;

    float es = expf(sc[0]);

    bf16x8 wh[2][4], wl[2][4];
    #pragma unroll
    for (int s = 0; s < 2; ++s)
        #pragma unroll
        for (int t = 0; t < 4; ++t) {
            const float* wp = W + (t * 16 + col) * 64 + s * 32 + grp * 8;
            split8(*(const float4*)wp, *(const float4*)(wp + 4), wh[s][t], wl[s][t]);
        }

    f32x4 acc[4];
    #pragma unroll
    for (int t = 0; t < 4; ++t) {
        float bv = bias[t * 16 + col];
        acc[t] = (f32x4){bv, bv, bv, bv};
    }

    int arow = node0 + col;
    if (arow >= n) arow = n - 1;                 // tail clamp; stores guarded
    #pragma unroll
    for (int s = 0; s < 2; ++s) {
        const float* ap = tbl + (size_t)arow * 64 + s * 32 + grp * 8;
        float4 a0 = *(const float4*)ap;
        float4 a1 = *(const float4*)(ap + 4);
        if (RELU) {
            a0.x = fmaxf(a0.x, 0.f); a0.y = fmaxf(a0.y, 0.f);
            a0.z = fmaxf(a0.z, 0.f); a0.w = fmaxf(a0.w, 0.f);
            a1.x = fmaxf(a1.x, 0.f); a1.y = fmaxf(a1.y, 0.f);
            a1.z = fmaxf(a1.z, 0.f); a1.w = fmaxf(a1.w, 0.f);
        }
        bf16x8 ah, al;
        split8(a0, a1, ah, al);
        #pragma unroll
        for (int t = 0; t < 4; ++t) {
            acc[t] = __builtin_amdgcn_mfma_f32_16x16x32_bf16(ah, wh[s][t], acc[t], 0, 0, 0);
            acc[t] = __builtin_amdgcn_mfma_f32_16x16x32_bf16(al, wh[s][t], acc[t], 0, 0, 0);
            acc[t] = __builtin_amdgcn_mfma_f32_16x16x32_bf16(ah, wl[s][t], acc[t], 0, 0, 0);
        }
    }

    // epilogue: per-row (row = grp*4 + r) time/scale, all in-register
    float tot[4];
    #pragma unroll
    for (int r = 0; r < 4; ++r) {
        float s = 0.f;
        #pragma unroll
        for (int t = 0; t < 4; ++t) s += acc[t][r] * acc[t][r];
        tot[r] = s;
    }
    #pragma unroll
    for (int d2 = 1; d2 < 16; d2 <<= 1) {
        #pragma unroll
        for (int r = 0; r < 4; ++r) tot[r] += __shfl_xor(tot[r], d2);
    }
    float tm[4], rs[4];
    #pragma unroll
    for (int r = 0; r < 4; ++r) {
        float h0 = __shfl(acc[0][r], lane & 48);   // col 0 of this group's rows
        tm[r] = es / (1.f + expf(-h0)) + 1.1f;
        float sq = fmaxf(tot[r] - h0 * h0, EPS);
        rs[r] = sqrtf((tm[r] * tm[r] - 1.f) / sq);
    }
    #pragma unroll
    for (int t = 0; t < 4; ++t) {
        #pragma unroll
        for (int r = 0; r < 4; ++r) {
            int row = node0 + grp * 4 + r;
            if (row < n) {
                int j = t * 16 + col;
                float v = (j == 0) ? tm[r] : acc[t][r] * rs[r];
                out[(size_t)row * 64 + j] = v;   // table for next agg: keep cached
            }
        }
    }
}

// ---------------- Aggregation ----------------
template <int FINAL>
__global__ __launch_bounds__(256) void k_agg(const float* __restrict__ t,
                                             const int* __restrict__ off,
                                             const float2* __restrict__ epack,
                                             const float* __restrict__ h1,
                                             float* __restrict__ out, int n) {
    __shared__ __align__(16) float2 ebuf[4][64];
    int lane = threadIdx.x & 63, wv = threadIdx.x >> 6;
    int node = blockIdx.x * 4 + wv;
    if (node >= n) return;
    int s0 = off[node], s1 = off[node + 1];
    float acc0 = 0.f, acc1 = 0.f, acc2 = 0.f, acc3 = 0.f;
    for (int base = s0; base < s1; base += 64) {
        int cnt = min(s1 - base, 64);
        if (lane < cnt)
            ebuf[wv][lane] = epack[base + lane];
        int j = 0;
        for (; j + 8 <= cnt; j += 8) {
            float4 a = *(const float4*)&ebuf[wv][j];
            float4 c = *(const float4*)&ebuf[wv][j + 2];
            float4 e = *(const float4*)&ebuf[wv][j + 4];
            float4 g = *(const float4*)&ebuf[wv][j + 6];
            acc0 += a.y * t[__float_as_int(a.x) * 64 + lane];
            acc1 += a.w * t[__float_as_int(a.z) * 64 + lane];
            acc2 += c.y * t[__float_as_int(c.x) * 64 + lane];
            acc3 += c.w * t[__float_as_int(c.z) * 64 + lane];
            acc0 += e.y * t[__float_as_int(e.x) * 64 + lane];
            acc1 += e.w * t[__float_as_int(e.z) * 64 + lane];
            acc2 += g.y * t[__float_as_int(g.x) * 64 + lane];
            acc3 += g.w * t[__float_as_int(g.z) * 64 + lane];
        }
        for (; j + 2 <= cnt; j += 2) {
            float4 a = *(const float4*)&ebuf[wv][j];
            acc0 += a.y * t[__float_as_int(a.x) * 64 + lane];
            acc1 += a.w * t[__float_as_int(a.z) * 64 + lane];
        }
        if (j < cnt) {
            float2 e1 = ebuf[wv][j];
            acc0 += e1.y * t[__float_as_int(e1.x) * 64 + lane];
        }
    }
    float acc = (acc0 + acc1) + (acc2 + acc3);
    float q = (lane == 0) ? -acc * acc : acc * acc;
    float denom = sqrtf(fmaxf(fabsf(wave_sum64(q)), EPS));
    float h = acc / denom;
    if (FINAL) {
        float v = h1[node * 64 + lane] + h;
        float q2 = (lane == 0) ? -v * v : v * v;
        float denom2 = sqrtf(fmaxf(fabsf(wave_sum64(q2)), EPS));
        __builtin_nontemporal_store(v / denom2, &out[node * 64 + lane]);
    } else {
        __builtin_nontemporal_store(h, &out[node * 64 + lane]);
    }
}

extern "C" void kernel_launch(void* const* d_in, const int* in_sizes, int n_in,
                              void* d_out, int out_size, void* d_ws, size_t ws_size,
                              hipStream_t stream) {
    const float* x  = (const float*)d_in[0];
    const int*   ei = (const int*)d_in[1];
    const float* wE = (const float*)d_in[2];
    const float* W1 = (const float*)d_in[3];
    const float* b1 = (const float*)d_in[4];
    const float* s1 = (const float*)d_in[5];
    const float* W2 = (const float*)d_in[6];
    const float* b2 = (const float*)d_in[7];
    const float* s2 = (const float*)d_in[8];
    float* out = (float*)d_out;

    const int N = in_sizes[0] / (D - 1);
    const int E = in_sizes[2];
    const int* src = ei;
    const int* dst = ei + E;
    const int nbuck = (N + BNODES - 1) >> BSH;

    char* ws = (char*)d_ws;
    float* B1 = (float*)ws;                                   // table A (also bucket tmp)
    float* B2 = B1 + (size_t)N * D;                           // table B (P, then h1)
    unsigned long long* epack = (unsigned long long*)(B2 + (size_t)N * D);
    int* off  = (int*)(epack + E);                            // N+1
    int* deg  = off + (N + 1);                                // N
    int* gcur = deg + N;                                      // nbuck
    int* sums = gcur + 128;                                   // <=128
    unsigned long long* tmp = (unsigned long long*)B1;        // E x 8B (pre-linear)

    hipMemsetAsync(deg, 0, (size_t)N * sizeof(int), stream);

    int gE4 = (E + 1023) / 1024;
    int nb = (N + 1023) / 1024;
    int gL = (N + 63) / 64;
    int gA = (N + 3) / 4;

    k_hist<<<gE4, 256, 0, stream>>>(dst, deg, E);
    k_scan1<<<nb, 1024, 0, stream>>>(deg, off, sums, N);
    k_scan2<<<1, 128, 0, stream>>>(sums, nb);
    k_scan3<<<nb, 1024, 0, stream>>>(off, sums, N, E);
    k_binit<<<1, 128, 0, stream>>>(off, gcur, N, nbuck);
    k_bucketA<<<gE4, 256, 0, stream>>>(src, dst, wE, gcur, tmp, E, nbuck);
    k_bucketB<<<nbuck, 1024, 0, stream>>>(tmp, off, epack, N);

    k_embed<<<gL, 256, 0, stream>>>(x, B2, N);                         // x -> P (B2)
    k_lin_mfma<0><<<gL, 256, 0, stream>>>(B2, W1, b1, s1, B1, N);      // P -> t1 (B1)
    k_agg<0><<<gA, 256, 0, stream>>>(B1, off, (const float2*)epack, nullptr, B2, N); // h1 (B2)
    k_lin_mfma<1><<<gL, 256, 0, stream>>>(B2, W2, b2, s2, B1, N);      // relu(h1) -> t2 (B1)
    k_agg<1><<<gA, 256, 0, stream>>>(B1, off, (const float2*)epack, B2, out, N);
}

// Round 7
// 249.519 us; speedup vs baseline: 3.3246x; 1.1586x over previous
//
#include <hip/hip_runtime.h>
#include <hip/hip_bf16.h>

#define D 64
#define EPS 1e-8f
#define BSH 10                         // nodes per bucket = 1024
#define BNODES (1 << BSH)

typedef __attribute__((ext_vector_type(8))) short bf16x8;
typedef __attribute__((ext_vector_type(4))) float f32x4;

__device__ __forceinline__ float wave_sum64(float v) {
    #pragma unroll
    for (int d = 1; d < 64; d <<= 1) v += __shfl_xor(v, d);
    return v;
}

__device__ __forceinline__ unsigned short f2bf_rn(float f) {
    unsigned u = __float_as_uint(f);
    return (unsigned short)((u + 0x7FFFu + ((u >> 16) & 1u)) >> 16);
}

// split 8 f32 into hi/lo bf16 (truncation; hi+lo carries ~16 mantissa bits)
__device__ __forceinline__ void split8(float4 a, float4 b, bf16x8& h, bf16x8& l) {
    float f[8] = {a.x, a.y, a.z, a.w, b.x, b.y, b.z, b.w};
    #pragma unroll
    for (int i = 0; i < 8; ++i) {
        unsigned u = __float_as_uint(f[i]);
        float hf = __uint_as_float(u & 0xFFFF0000u);
        unsigned lu = __float_as_uint(f[i] - hf);
        h[i] = (short)(u >> 16);
        l[i] = (short)(lu >> 16);
    }
}

// ---- Pass 0: per-bucket edge counts (LDS-aggregated) ----
__global__ __launch_bounds__(256) void k_bcount(const int* __restrict__ dst,
                                                int* __restrict__ bcnt,
                                                int e, int nbuck) {
    __shared__ int cnt[128];
    int tid = threadIdx.x;
    if (tid < 128) cnt[tid] = 0;
    __syncthreads();
    int i0 = blockIdx.x * 1024 + tid;
    #pragma unroll
    for (int u = 0; u < 4; ++u) {
        int i = i0 + u * 256;
        if (i < e) atomicAdd(&cnt[dst[i] >> BSH], 1);
    }
    __syncthreads();
    if (tid < nbuck && cnt[tid]) atomicAdd(&bcnt[tid], cnt[tid]);
}

// ---- scan bucket counts -> bstart[0..nbuck], gcur copy, off[n]=e ----
__global__ __launch_bounds__(128) void k_bscan(const int* __restrict__ bcnt,
                                               int* __restrict__ bstart,
                                               int* __restrict__ gcur,
                                               int* __restrict__ off,
                                               int n, int e, int nbuck) {
    __shared__ int sm[128];
    int tid = threadIdx.x;
    int v = (tid < nbuck) ? bcnt[tid] : 0;
    sm[tid] = v;
    __syncthreads();
    #pragma unroll
    for (int d = 1; d < 128; d <<= 1) {
        int t = (tid >= d) ? sm[tid - d] : 0;
        __syncthreads();
        sm[tid] += t;
        __syncthreads();
    }
    int excl = sm[tid] - v;
    if (tid < nbuck) { bstart[tid] = excl; gcur[tid] = excl; }
    if (tid == 0) { bstart[nbuck] = e; off[n] = e; }
}

// ---- Pass A: bucket edges by dst>>BSH; pack [w:32][dstlow:10 @20][src:20] ----
__global__ __launch_bounds__(256) void k_bucketA(const int* __restrict__ src,
                                                 const int* __restrict__ dst,
                                                 const float* __restrict__ w,
                                                 int* __restrict__ gcur,
                                                 unsigned long long* __restrict__ tmp,
                                                 int e, int nbuck) {
    __shared__ int cnt[128];
    __shared__ int base[128];
    int tid = threadIdx.x;
    if (tid < 128) cnt[tid] = 0;
    __syncthreads();
    int i0 = blockIdx.x * 1024 + tid;
    int bkt[4], rnk[4];
    #pragma unroll
    for (int u = 0; u < 4; ++u) {
        int i = i0 + u * 256;
        if (i < e) {
            int b = dst[i] >> BSH;
            bkt[u] = b;
            rnk[u] = atomicAdd(&cnt[b], 1);
        }
    }
    __syncthreads();
    if (tid < 128) {
        int c = cnt[tid];
        base[tid] = c ? atomicAdd(&gcur[tid], c) : 0;
    }
    __syncthreads();
    #pragma unroll
    for (int u = 0; u < 4; ++u) {
        int i = i0 + u * 256;
        if (i < e) {
            unsigned long long pk =
                ((unsigned long long)__float_as_uint(w[i]) << 32)
                | (unsigned int)(src[i] | ((dst[i] & (BNODES - 1)) << 20));
            tmp[base[bkt[u]] + rnk[u]] = pk;
        }
    }
}

// ---- Pass B: per bucket: LDS node-hist + scan -> off, then scatter ----
__global__ __launch_bounds__(1024) void k_bucketB(const unsigned long long* __restrict__ tmp,
                                                  const int* __restrict__ bstart,
                                                  int* __restrict__ off,
                                                  unsigned long long* __restrict__ epack,
                                                  int n) {
    __shared__ int cur[BNODES];
    __shared__ int sm[BNODES];
    int b = blockIdx.x;
    int v0 = b << BSH;
    int nv = min(BNODES, n - v0);
    int tid = threadIdx.x;
    cur[tid] = 0;
    __syncthreads();
    int s0 = bstart[b], s1 = bstart[b + 1];
    for (int i = s0 + tid; i < s1; i += 1024)
        atomicAdd(&cur[((unsigned)tmp[i] >> 20) & (BNODES - 1)], 1);
    __syncthreads();
    int v = cur[tid];
    sm[tid] = v;
    __syncthreads();
    #pragma unroll
    for (int d = 1; d < BNODES; d <<= 1) {
        int t = (tid >= d) ? sm[tid - d] : 0;
        __syncthreads();
        sm[tid] += t;
        __syncthreads();
    }
    int node_off = s0 + sm[tid] - v;
    if (tid < nv) off[v0 + tid] = node_off;
    cur[tid] = node_off;
    __syncthreads();
    for (int i = s0 + tid; i < s1; i += 1024) {
        unsigned long long pk = tmp[i];
        int dl = ((unsigned)pk >> 20) & (BNODES - 1);
        int pos = atomicAdd(&cur[dl], 1);
        epack[pos] = pk & 0xFFFFFFFFC00FFFFFULL;
    }
}

// ---------------- Hyperboloid embed: x(N x 63) -> P(N x 64) f32 ----------------
__global__ __launch_bounds__(256) void k_embed(const float* __restrict__ x,
                                               float* __restrict__ P, int n) {
    int lane = threadIdx.x & 63, wv = threadIdx.x >> 6;
    int node0 = blockIdx.x * 64 + wv * 16;
    int node1 = min(node0 + 16, n);
    for (int node = node0; node < node1; ++node) {
        float xv = (lane >= 1) ? x[(size_t)node * 63 + (lane - 1)] : 0.f;
        float nrm2 = wave_sum64(xv * xv);
        float nrm = fmaxf(sqrtf(nrm2), EPS);
        float sh = sinhf(nrm);
        float ps = sh * xv / nrm;
        float pt = sqrtf(1.f + sh * sh);
        P[(size_t)node * 64 + lane] = (lane == 0) ? pt : ps;
    }
}

// ---------------- Lorentz linear via split-bf16 MFMA; bf16 output table ------
template <int RELU>
__global__ __launch_bounds__(256) void k_lin_mfma(const float* __restrict__ tbl,
                                                  const float* __restrict__ W,
                                                  const float* __restrict__ bias,
                                                  const float* __restrict__ sc,
                                                  unsigned short* __restrict__ out, int n) {
    int lane = threadIdx.x & 63, wv = threadIdx.x >> 6;
    int col = lane & 15, grp = lane >> 4;
    int node0 = blockIdx.x * 64 + wv * 16;
    if (node0 >= n) return;

    float es = expf(sc[0]);

    bf16x8 wh[2][4], wl[2][4];
    #pragma unroll
    for (int s = 0; s < 2; ++s)
        #pragma unroll
        for (int t = 0; t < 4; ++t) {
            const float* wp = W + (t * 16 + col) * 64 + s * 32 + grp * 8;
            split8(*(const float4*)wp, *(const float4*)(wp + 4), wh[s][t], wl[s][t]);
        }

    f32x4 acc[4];
    #pragma unroll
    for (int t = 0; t < 4; ++t) {
        float bv = bias[t * 16 + col];
        acc[t] = (f32x4){bv, bv, bv, bv};
    }

    int arow = node0 + col;
    if (arow >= n) arow = n - 1;
    #pragma unroll
    for (int s = 0; s < 2; ++s) {
        const float* ap = tbl + (size_t)arow * 64 + s * 32 + grp * 8;
        float4 a0 = *(const float4*)ap;
        float4 a1 = *(const float4*)(ap + 4);
        if (RELU) {
            a0.x = fmaxf(a0.x, 0.f); a0.y = fmaxf(a0.y, 0.f);
            a0.z = fmaxf(a0.z, 0.f); a0.w = fmaxf(a0.w, 0.f);
            a1.x = fmaxf(a1.x, 0.f); a1.y = fmaxf(a1.y, 0.f);
            a1.z = fmaxf(a1.z, 0.f); a1.w = fmaxf(a1.w, 0.f);
        }
        bf16x8 ah, al;
        split8(a0, a1, ah, al);
        #pragma unroll
        for (int t = 0; t < 4; ++t) {
            acc[t] = __builtin_amdgcn_mfma_f32_16x16x32_bf16(ah, wh[s][t], acc[t], 0, 0, 0);
            acc[t] = __builtin_amdgcn_mfma_f32_16x16x32_bf16(al, wh[s][t], acc[t], 0, 0, 0);
            acc[t] = __builtin_amdgcn_mfma_f32_16x16x32_bf16(ah, wl[s][t], acc[t], 0, 0, 0);
        }
    }

    float tot[4];
    #pragma unroll
    for (int r = 0; r < 4; ++r) {
        float s = 0.f;
        #pragma unroll
        for (int t = 0; t < 4; ++t) s += acc[t][r] * acc[t][r];
        tot[r] = s;
    }
    #pragma unroll
    for (int d2 = 1; d2 < 16; d2 <<= 1) {
        #pragma unroll
        for (int r = 0; r < 4; ++r) tot[r] += __shfl_xor(tot[r], d2);
    }
    float tm[4], rs[4];
    #pragma unroll
    for (int r = 0; r < 4; ++r) {
        float h0 = __shfl(acc[0][r], lane & 48);
        tm[r] = es / (1.f + expf(-h0)) + 1.1f;
        float sq = fmaxf(tot[r] - h0 * h0, EPS);
        rs[r] = sqrtf((tm[r] * tm[r] - 1.f) / sq);
    }
    #pragma unroll
    for (int t = 0; t < 4; ++t) {
        #pragma unroll
        for (int r = 0; r < 4; ++r) {
            int row = node0 + grp * 4 + r;
            if (row < n) {
                int j = t * 16 + col;
                float v = (j == 0) ? tm[r] : acc[t][r] * rs[r];
                out[(size_t)row * 64 + j] = f2bf_rn(v);
            }
        }
    }
}

// ---------------- Aggregation: bf16 table gather, f32 accumulate -------------
template <int FINAL>
__global__ __launch_bounds__(256) void k_agg(const unsigned short* __restrict__ t,
                                             const int* __restrict__ off,
                                             const float2* __restrict__ epack,
                                             const float* __restrict__ h1,
                                             float* __restrict__ out, int n) {
    __shared__ __align__(16) float2 ebuf[4][64];
    int lane = threadIdx.x & 63, wv = threadIdx.x >> 6;
    int node = blockIdx.x * 4 + wv;
    if (node >= n) return;
    int s0 = off[node], s1 = off[node + 1];
    float acc0 = 0.f, acc1 = 0.f, acc2 = 0.f, acc3 = 0.f;
    #define GET(idx) __uint_as_float((unsigned)t[(size_t)(idx) * 64 + lane] << 16)
    for (int base = s0; base < s1; base += 64) {
        int cnt = min(s1 - base, 64);
        if (lane < cnt)
            ebuf[wv][lane] = epack[base + lane];
        int j = 0;
        for (; j + 8 <= cnt; j += 8) {
            float4 a = *(const float4*)&ebuf[wv][j];
            float4 c = *(const float4*)&ebuf[wv][j + 2];
            float4 e = *(const float4*)&ebuf[wv][j + 4];
            float4 g = *(const float4*)&ebuf[wv][j + 6];
            acc0 += a.y * GET(__float_as_int(a.x));
            acc1 += a.w * GET(__float_as_int(a.z));
            acc2 += c.y * GET(__float_as_int(c.x));
            acc3 += c.w * GET(__float_as_int(c.z));
            acc0 += e.y * GET(__float_as_int(e.x));
            acc1 += e.w * GET(__float_as_int(e.z));
            acc2 += g.y * GET(__float_as_int(g.x));
            acc3 += g.w * GET(__float_as_int(g.z));
        }
        for (; j + 2 <= cnt; j += 2) {
            float4 a = *(const float4*)&ebuf[wv][j];
            acc0 += a.y * GET(__float_as_int(a.x));
            acc1 += a.w * GET(__float_as_int(a.z));
        }
        if (j < cnt) {
            float2 e1 = ebuf[wv][j];
            acc0 += e1.y * GET(__float_as_int(e1.x));
        }
    }
    #undef GET
    float acc = (acc0 + acc1) + (acc2 + acc3);
    float q = (lane == 0) ? -acc * acc : acc * acc;
    float denom = sqrtf(fmaxf(fabsf(wave_sum64(q)), EPS));
    float h = acc / denom;
    if (FINAL) {
        float vv = h1[(size_t)node * 64 + lane] + h;
        float q2 = (lane == 0) ? -vv * vv : vv * vv;
        float denom2 = sqrtf(fmaxf(fabsf(wave_sum64(q2)), EPS));
        __builtin_nontemporal_store(vv / denom2, &out[(size_t)node * 64 + lane]);
    } else {
        __builtin_nontemporal_store(h, &out[(size_t)node * 64 + lane]);
    }
}

extern "C" void kernel_launch(void* const* d_in, const int* in_sizes, int n_in,
                              void* d_out, int out_size, void* d_ws, size_t ws_size,
                              hipStream_t stream) {
    const float* x  = (const float*)d_in[0];
    const int*   ei = (const int*)d_in[1];
    const float* wE = (const float*)d_in[2];
    const float* W1 = (const float*)d_in[3];
    const float* b1 = (const float*)d_in[4];
    const float* s1 = (const float*)d_in[5];
    const float* W2 = (const float*)d_in[6];
    const float* b2 = (const float*)d_in[7];
    const float* s2 = (const float*)d_in[8];
    float* out = (float*)d_out;

    const int N = in_sizes[0] / (D - 1);
    const int E = in_sizes[2];
    const int* src = ei;
    const int* dst = ei + E;
    const int nbuck = (N + BNODES - 1) >> BSH;

    char* ws = (char*)d_ws;
    // region1: bf16 table T (N*64*2B) aliased with bucket tmp (E*8B)
    size_t sz1 = (size_t)N * D * 2;
    size_t szt = (size_t)E * 8;
    if (szt > sz1) sz1 = szt;
    sz1 = (sz1 + 255) & ~(size_t)255;
    unsigned short* T = (unsigned short*)ws;
    unsigned long long* tmp = (unsigned long long*)ws;
    float* B2 = (float*)(ws + sz1);                           // f32 P, then h1
    unsigned long long* epack = (unsigned long long*)((char*)B2 + (size_t)N * D * 4);
    int* off    = (int*)(epack + E);                          // N+1
    int* bcnt   = off + (N + 1);                              // 128
    int* bstart = bcnt + 128;                                 // 129
    int* gcur   = bstart + 132;                               // 128

    hipMemsetAsync(bcnt, 0, 128 * sizeof(int), stream);

    int gE4 = (E + 1023) / 1024;
    int gL = (N + 63) / 64;
    int gA = (N + 3) / 4;

    k_bcount<<<gE4, 256, 0, stream>>>(dst, bcnt, E, nbuck);
    k_bscan<<<1, 128, 0, stream>>>(bcnt, bstart, gcur, off, N, E, nbuck);
    k_bucketA<<<gE4, 256, 0, stream>>>(src, dst, wE, gcur, tmp, E, nbuck);
    k_bucketB<<<nbuck, 1024, 0, stream>>>(tmp, bstart, off, epack, N);

    k_embed<<<gL, 256, 0, stream>>>(x, B2, N);                       // x -> P (f32)
    k_lin_mfma<0><<<gL, 256, 0, stream>>>(B2, W1, b1, s1, T, N);     // P -> t1 (bf16)
    k_agg<0><<<gA, 256, 0, stream>>>(T, off, (const float2*)epack, nullptr, B2, N); // h1 (f32)
    k_lin_mfma<1><<<gL, 256, 0, stream>>>(B2, W2, b2, s2, T, N);     // relu(h1) -> t2 (bf16)
    k_agg<1><<<gA, 256, 0, stream>>>(T, off, (const float2*)epack, B2, out, N);
}

// Round 8
// 234.213 us; speedup vs baseline: 3.5418x; 1.0653x over previous
//
#include <hip/hip_runtime.h>
#include <hip/hip_bf16.h>

#define D 64
#define EPS 1e-8f
#define BSH 10                         // nodes per bucket = 1024
#define BNODES (1 << BSH)
#define ABLK 4096                      // edges per bucketA block

typedef __attribute__((ext_vector_type(8))) short bf16x8;
typedef __attribute__((ext_vector_type(4))) float f32x4;

__device__ __forceinline__ float wave_sum64(float v) {
    #pragma unroll
    for (int d = 1; d < 64; d <<= 1) v += __shfl_xor(v, d);
    return v;
}

__device__ __forceinline__ unsigned short f2bf_rn(float f) {
    unsigned u = __float_as_uint(f);
    return (unsigned short)((u + 0x7FFFu + ((u >> 16) & 1u)) >> 16);
}

// split 8 f32 into hi/lo bf16 (truncation; hi+lo carries ~16 mantissa bits)
__device__ __forceinline__ void split8(float4 a, float4 b, bf16x8& h, bf16x8& l) {
    float f[8] = {a.x, a.y, a.z, a.w, b.x, b.y, b.z, b.w};
    #pragma unroll
    for (int i = 0; i < 8; ++i) {
        unsigned u = __float_as_uint(f[i]);
        float hf = __uint_as_float(u & 0xFFFF0000u);
        unsigned lu = __float_as_uint(f[i] - hf);
        h[i] = (short)(u >> 16);
        l[i] = (short)(lu >> 16);
    }
}

// ---- Pass 0: per-bucket edge counts (LDS-aggregated) ----
__global__ __launch_bounds__(256) void k_bcount(const int* __restrict__ dst,
                                                int* __restrict__ bcnt,
                                                int e, int nbuck) {
    __shared__ int cnt[128];
    int tid = threadIdx.x;
    if (tid < 128) cnt[tid] = 0;
    __syncthreads();
    int i0 = blockIdx.x * 1024 + tid;
    #pragma unroll
    for (int u = 0; u < 4; ++u) {
        int i = i0 + u * 256;
        if (i < e) atomicAdd(&cnt[dst[i] >> BSH], 1);
    }
    __syncthreads();
    if (tid < nbuck && cnt[tid]) atomicAdd(&bcnt[tid], cnt[tid]);
}

// ---- scan bucket counts -> bstart[0..nbuck], gcur copy, off[n]=e ----
__global__ __launch_bounds__(128) void k_bscan(const int* __restrict__ bcnt,
                                               int* __restrict__ bstart,
                                               int* __restrict__ gcur,
                                               int* __restrict__ off,
                                               int n, int e, int nbuck) {
    __shared__ int sm[128];
    int tid = threadIdx.x;
    int v = (tid < nbuck) ? bcnt[tid] : 0;
    sm[tid] = v;
    __syncthreads();
    #pragma unroll
    for (int d = 1; d < 128; d <<= 1) {
        int t = (tid >= d) ? sm[tid - d] : 0;
        __syncthreads();
        sm[tid] += t;
        __syncthreads();
    }
    int excl = sm[tid] - v;
    if (tid < nbuck) { bstart[tid] = excl; gcur[tid] = excl; }
    if (tid == 0) { bstart[nbuck] = e; off[n] = e; }
}

// ---- Pass A: bucket edges by dst>>BSH; pack [w:32][dstlow:10 @20][src:20] ----
__global__ __launch_bounds__(256) void k_bucketA(const int* __restrict__ src,
                                                 const int* __restrict__ dst,
                                                 const float* __restrict__ w,
                                                 int* __restrict__ gcur,
                                                 unsigned long long* __restrict__ tmp,
                                                 int e, int nbuck) {
    __shared__ int cnt[128];
    __shared__ int base[128];
    int tid = threadIdx.x;
    if (tid < 128) cnt[tid] = 0;
    __syncthreads();
    int i0 = blockIdx.x * ABLK + tid;
    int bkt[16], rnk[16];
    #pragma unroll
    for (int u = 0; u < 16; ++u) {
        int i = i0 + u * 256;
        if (i < e) {
            int b = dst[i] >> BSH;
            bkt[u] = b;
            rnk[u] = atomicAdd(&cnt[b], 1);
        }
    }
    __syncthreads();
    if (tid < 128) {
        int c = cnt[tid];
        base[tid] = c ? atomicAdd(&gcur[tid], c) : 0;
    }
    __syncthreads();
    #pragma unroll
    for (int u = 0; u < 16; ++u) {
        int i = i0 + u * 256;
        if (i < e) {
            unsigned long long pk =
                ((unsigned long long)__float_as_uint(w[i]) << 32)
                | (unsigned int)(src[i] | ((dst[i] & (BNODES - 1)) << 20));
            tmp[base[bkt[u]] + rnk[u]] = pk;
        }
    }
}

// ---- Pass B: per bucket: LDS node-hist + scan -> off, then scatter ----
__global__ __launch_bounds__(1024) void k_bucketB(const unsigned long long* __restrict__ tmp,
                                                  const int* __restrict__ bstart,
                                                  int* __restrict__ off,
                                                  unsigned long long* __restrict__ epack,
                                                  int n) {
    __shared__ int cur[BNODES];
    __shared__ int sm[BNODES];
    int b = blockIdx.x;
    int v0 = b << BSH;
    int nv = min(BNODES, n - v0);
    int tid = threadIdx.x;
    cur[tid] = 0;
    __syncthreads();
    int s0 = bstart[b], s1 = bstart[b + 1];
    for (int i = s0 + tid; i < s1; i += 1024)
        atomicAdd(&cur[((unsigned)tmp[i] >> 20) & (BNODES - 1)], 1);
    __syncthreads();
    int v = cur[tid];
    sm[tid] = v;
    __syncthreads();
    #pragma unroll
    for (int d = 1; d < BNODES; d <<= 1) {
        int t = (tid >= d) ? sm[tid - d] : 0;
        __syncthreads();
        sm[tid] += t;
        __syncthreads();
    }
    int node_off = s0 + sm[tid] - v;
    if (tid < nv) off[v0 + tid] = node_off;
    cur[tid] = node_off;
    __syncthreads();
    for (int i = s0 + tid; i < s1; i += 1024) {
        unsigned long long pk = tmp[i];
        int dl = ((unsigned)pk >> 20) & (BNODES - 1);
        int pos = atomicAdd(&cur[dl], 1);
        epack[pos] = pk & 0xFFFFFFFFC00FFFFFULL;
    }
}

// ---------------- Hyperboloid embed: x(N x 63) -> P(N x 64) f32 ----------------
__global__ __launch_bounds__(256) void k_embed(const float* __restrict__ x,
                                               float* __restrict__ P, int n) {
    int lane = threadIdx.x & 63, wv = threadIdx.x >> 6;
    int node0 = blockIdx.x * 64 + wv * 16;
    int node1 = min(node0 + 16, n);
    for (int node = node0; node < node1; ++node) {
        float xv = (lane >= 1) ? x[(size_t)node * 63 + (lane - 1)] : 0.f;
        float nrm2 = wave_sum64(xv * xv);
        float nrm = fmaxf(sqrtf(nrm2), EPS);
        float sh = sinhf(nrm);
        float ps = sh * xv / nrm;
        float pt = sqrtf(1.f + sh * sh);
        P[(size_t)node * 64 + lane] = (lane == 0) ? pt : ps;
    }
}

// ---------------- Lorentz linear via split-bf16 MFMA; bf16 output table ------
template <int RELU>
__global__ __launch_bounds__(256) void k_lin_mfma(const float* __restrict__ tbl,
                                                  const float* __restrict__ W,
                                                  const float* __restrict__ bias,
                                                  const float* __restrict__ sc,
                                                  unsigned short* __restrict__ out, int n) {
    int lane = threadIdx.x & 63, wv = threadIdx.x >> 6;
    int col = lane & 15, grp = lane >> 4;
    int node0 = blockIdx.x * 64 + wv * 16;
    if (node0 >= n) return;

    float es = expf(sc[0]);

    bf16x8 wh[2][4], wl[2][4];
    #pragma unroll
    for (int s = 0; s < 2; ++s)
        #pragma unroll
        for (int t = 0; t < 4; ++t) {
            const float* wp = W + (t * 16 + col) * 64 + s * 32 + grp * 8;
            split8(*(const float4*)wp, *(const float4*)(wp + 4), wh[s][t], wl[s][t]);
        }

    f32x4 acc[4];
    #pragma unroll
    for (int t = 0; t < 4; ++t) {
        float bv = bias[t * 16 + col];
        acc[t] = (f32x4){bv, bv, bv, bv};
    }

    int arow = node0 + col;
    if (arow >= n) arow = n - 1;
    #pragma unroll
    for (int s = 0; s < 2; ++s) {
        const float* ap = tbl + (size_t)arow * 64 + s * 32 + grp * 8;
        float4 a0 = *(const float4*)ap;
        float4 a1 = *(const float4*)(ap + 4);
        if (RELU) {
            a0.x = fmaxf(a0.x, 0.f); a0.y = fmaxf(a0.y, 0.f);
            a0.z = fmaxf(a0.z, 0.f); a0.w = fmaxf(a0.w, 0.f);
            a1.x = fmaxf(a1.x, 0.f); a1.y = fmaxf(a1.y, 0.f);
            a1.z = fmaxf(a1.z, 0.f); a1.w = fmaxf(a1.w, 0.f);
        }
        bf16x8 ah, al;
        split8(a0, a1, ah, al);
        #pragma unroll
        for (int t = 0; t < 4; ++t) {
            acc[t] = __builtin_amdgcn_mfma_f32_16x16x32_bf16(ah, wh[s][t], acc[t], 0, 0, 0);
            acc[t] = __builtin_amdgcn_mfma_f32_16x16x32_bf16(al, wh[s][t], acc[t], 0, 0, 0);
            acc[t] = __builtin_amdgcn_mfma_f32_16x16x32_bf16(ah, wl[s][t], acc[t], 0, 0, 0);
        }
    }

    float tot[4];
    #pragma unroll
    for (int r = 0; r < 4; ++r) {
        float s = 0.f;
        #pragma unroll
        for (int t = 0; t < 4; ++t) s += acc[t][r] * acc[t][r];
        tot[r] = s;
    }
    #pragma unroll
    for (int d2 = 1; d2 < 16; d2 <<= 1) {
        #pragma unroll
        for (int r = 0; r < 4; ++r) tot[r] += __shfl_xor(tot[r], d2);
    }
    float tm[4], rs[4];
    #pragma unroll
    for (int r = 0; r < 4; ++r) {
        float h0 = __shfl(acc[0][r], lane & 48);
        tm[r] = es / (1.f + expf(-h0)) + 1.1f;
        float sq = fmaxf(tot[r] - h0 * h0, EPS);
        rs[r] = sqrtf((tm[r] * tm[r] - 1.f) / sq);
    }
    #pragma unroll
    for (int t = 0; t < 4; ++t) {
        #pragma unroll
        for (int r = 0; r < 4; ++r) {
            int row = node0 + grp * 4 + r;
            if (row < n) {
                int j = t * 16 + col;
                float v = (j == 0) ? tm[r] : acc[t][r] * rs[r];
                out[(size_t)row * 64 + j] = f2bf_rn(v);
            }
        }
    }
}

// ---------------- Aggregation: 4 edges/wave, quarter-wave per edge ----------
// Lane (q=lane>>4, sub=lane&15) loads dims [sub*4 .. sub*4+3] (uint2 = 4 bf16)
// of edge j+q's source row. Cross-quarter shfl reduce at the end.
template <int FINAL>
__global__ __launch_bounds__(256) void k_agg(const unsigned short* __restrict__ t,
                                             const int* __restrict__ off,
                                             const float2* __restrict__ epack,
                                             const float* __restrict__ h1,
                                             float* __restrict__ out, int n) {
    __shared__ __align__(16) float2 ebuf[4][64];
    int lane = threadIdx.x & 63, wv = threadIdx.x >> 6;
    int q = lane >> 4, sub = lane & 15;
    int node = blockIdx.x * 4 + wv;
    if (node >= n) return;
    int s0 = off[node], s1 = off[node + 1];
    float ax = 0.f, ay = 0.f, az = 0.f, aw = 0.f;
    for (int base = s0; base < s1; base += 64) {
        int c = min(s1 - base, 64);
        float2 ev = (lane < c) ? epack[base + lane] : make_float2(0.f, 0.f);
        ebuf[wv][lane] = ev;              // same-wave LDS: hw keeps ds order
        int c4 = (c + 3) & ~3;
        for (int j = 0; j < c4; j += 4) {
            float2 e = ebuf[wv][j + q];
            int src = __float_as_int(e.x);     // low 20 bits = src (dstlow cleared)
            float w = e.y;
            const unsigned* rp = (const unsigned*)(t + ((size_t)src << 6)) + sub * 2;
            uint2 rv = *(const uint2*)rp;      // 4 bf16
            ax += w * __uint_as_float(rv.x << 16);
            ay += w * __uint_as_float(rv.x & 0xFFFF0000u);
            az += w * __uint_as_float(rv.y << 16);
            aw += w * __uint_as_float(rv.y & 0xFFFF0000u);
        }
    }
    // cross-quarter reduce: lanes with same sub sum their 4 partials
    #pragma unroll
    for (int d2 = 16; d2 <= 32; d2 <<= 1) {
        ax += __shfl_xor(ax, d2);
        ay += __shfl_xor(ay, d2);
        az += __shfl_xor(az, d2);
        aw += __shfl_xor(aw, d2);
    }
    // Lorentz inner over 64 dims (dim0 negative)
    float s = ay * ay + az * az + aw * aw;
    s += (sub == 0) ? -ax * ax : ax * ax;
    #pragma unroll
    for (int d2 = 1; d2 < 16; d2 <<= 1) s += __shfl_xor(s, d2);
    float inv = 1.f / sqrtf(fmaxf(fabsf(s), EPS));
    float hx = ax * inv, hy = ay * inv, hz = az * inv, hw = aw * inv;
    if (FINAL) {
        float4 hv = *(const float4*)(h1 + (size_t)node * 64 + sub * 4);
        float vx = hv.x + hx, vy = hv.y + hy, vz = hv.z + hz, vw = hv.w + hw;
        float s2 = vy * vy + vz * vz + vw * vw;
        s2 += (sub == 0) ? -vx * vx : vx * vx;
        #pragma unroll
        for (int d2 = 1; d2 < 16; d2 <<= 1) s2 += __shfl_xor(s2, d2);
        float inv2 = 1.f / sqrtf(fmaxf(fabsf(s2), EPS));
        if (lane < 16) {
            float4 r = make_float4(vx * inv2, vy * inv2, vz * inv2, vw * inv2);
            *(float4*)(out + (size_t)node * 64 + sub * 4) = r;
        }
    } else {
        if (lane < 16) {
            float4 r = make_float4(hx, hy, hz, hw);
            *(float4*)(out + (size_t)node * 64 + sub * 4) = r;
        }
    }
}

extern "C" void kernel_launch(void* const* d_in, const int* in_sizes, int n_in,
                              void* d_out, int out_size, void* d_ws, size_t ws_size,
                              hipStream_t stream) {
    const float* x  = (const float*)d_in[0];
    const int*   ei = (const int*)d_in[1];
    const float* wE = (const float*)d_in[2];
    const float* W1 = (const float*)d_in[3];
    const float* b1 = (const float*)d_in[4];
    const float* s1 = (const float*)d_in[5];
    const float* W2 = (const float*)d_in[6];
    const float* b2 = (const float*)d_in[7];
    const float* s2 = (const float*)d_in[8];
    float* out = (float*)d_out;

    const int N = in_sizes[0] / (D - 1);
    const int E = in_sizes[2];
    const int* src = ei;
    const int* dst = ei + E;
    const int nbuck = (N + BNODES - 1) >> BSH;

    char* ws = (char*)d_ws;
    // region1: bf16 table T (N*64*2B) aliased with bucket tmp (E*8B)
    size_t sz1 = (size_t)N * D * 2;
    size_t szt = (size_t)E * 8;
    if (szt > sz1) sz1 = szt;
    sz1 = (sz1 + 255) & ~(size_t)255;
    unsigned short* T = (unsigned short*)ws;
    unsigned long long* tmp = (unsigned long long*)ws;
    float* B2 = (float*)(ws + sz1);                           // f32 P, then h1
    unsigned long long* epack = (unsigned long long*)((char*)B2 + (size_t)N * D * 4);
    int* off    = (int*)(epack + E);                          // N+1
    int* bcnt   = off + (N + 1);                              // 128
    int* bstart = bcnt + 128;                                 // 129
    int* gcur   = bstart + 132;                               // 128

    hipMemsetAsync(bcnt, 0, 128 * sizeof(int), stream);

    int gE4 = (E + 1023) / 1024;
    int gEA = (E + ABLK - 1) / ABLK;
    int gL = (N + 63) / 64;
    int gA = (N + 3) / 4;

    k_bcount<<<gE4, 256, 0, stream>>>(dst, bcnt, E, nbuck);
    k_bscan<<<1, 128, 0, stream>>>(bcnt, bstart, gcur, off, N, E, nbuck);
    k_bucketA<<<gEA, 256, 0, stream>>>(src, dst, wE, gcur, tmp, E, nbuck);
    k_bucketB<<<nbuck, 1024, 0, stream>>>(tmp, bstart, off, epack, N);

    k_embed<<<gL, 256, 0, stream>>>(x, B2, N);                       // x -> P (f32)
    k_lin_mfma<0><<<gL, 256, 0, stream>>>(B2, W1, b1, s1, T, N);     // P -> t1 (bf16)
    k_agg<0><<<gA, 256, 0, stream>>>(T, off, (const float2*)epack, nullptr, B2, N); // h1 (f32)
    k_lin_mfma<1><<<gL, 256, 0, stream>>>(B2, W2, b2, s2, T, N);     // relu(h1) -> t2 (bf16)
    k_agg<1><<<gA, 256, 0, stream>>>(T, off, (const float2*)epack, B2, out, N);
}